// Round 8
// baseline (468.623 us; speedup 1.0000x reference)
//
#include <hip/hip_runtime.h>
#include <hip/hip_bf16.h>
#include <cstdint>
#include <cstddef>

#define BN_EPS 1e-5f

typedef short short8 __attribute__((ext_vector_type(8)));
typedef float float16 __attribute__((ext_vector_type(16)));
typedef unsigned short ushort_t;

__device__ __forceinline__ float bf2f(ushort_t u) {
  return __uint_as_float(((unsigned int)u) << 16);
}
__device__ __forceinline__ ushort_t f2bf(float f) {
  unsigned int u = __float_as_uint(f);
  u += 0x7FFFu + ((u >> 16) & 1u);
  return (ushort_t)(u >> 16);
}

// ------------------------------------------------------------------
// PFN (fp32)
// ------------------------------------------------------------------

__global__ __launch_bounds__(256) void pfn_stats(
    const float* __restrict__ pillars, const float* __restrict__ lin_w,
    const float* __restrict__ lin_b, float* __restrict__ acc) {
  __shared__ float s_p[288];
  __shared__ float red[512];
  int tid = threadIdx.x;
  int c = tid & 63, rs = tid >> 6;
  float w[9];
#pragma unroll
  for (int d = 0; d < 9; ++d) w[d] = lin_w[c * 9 + d];
  float bl = lin_b[c];
  float s = 0.f, s2 = 0.f;
  long base_row = (long)blockIdx.x * 1024;
  for (int ch = 0; ch < 32; ++ch) {
    long crow = base_row + ch * 32;
    __syncthreads();
    for (int i = tid; i < 288; i += 256) s_p[i] = pillars[crow * 9 + i];
    __syncthreads();
#pragma unroll
    for (int k = 0; k < 8; ++k) {
      const float* pr = &s_p[(rs * 8 + k) * 9];
      float y = bl;
#pragma unroll
      for (int d = 0; d < 9; ++d) y += pr[d] * w[d];
      s += y;
      s2 += y * y;
    }
  }
  red[tid] = s;
  red[tid + 256] = s2;
  __syncthreads();
  if (rs == 0) {
    float ts = red[c] + red[c + 64] + red[c + 128] + red[c + 192];
    float t2 = red[256 + c] + red[256 + c + 64] + red[256 + c + 128] + red[256 + c + 192];
    atomicAdd(&acc[c], ts);
    atomicAdd(&acc[c + 64], t2);
  }
}

__global__ void pfn_finalize(const float* __restrict__ acc, const float* __restrict__ g,
                             const float* __restrict__ b, float* __restrict__ ss) {
  int c = threadIdx.x;  // 64 threads
  const float invN = 1.f / 640000.f;
  float m = acc[c] * invN;
  float v = acc[c + 64] * invN - m * m;
  v = fmaxf(v, 0.f);
  float inv = rsqrtf(v + BN_EPS);
  float sc = g[c] * inv;
  ss[c] = sc;
  ss[c + 64] = b[c] - m * sc;
}

__global__ __launch_bounds__(256) void pfn_feats(
    const float* __restrict__ pillars, const float* __restrict__ lin_w,
    const float* __restrict__ lin_b, const float* __restrict__ ss,
    float* __restrict__ feats) {
  __shared__ float s_p[1152];
  int tid = threadIdx.x;
  int c = tid & 63, pe = tid >> 6;
  long pb = (long)blockIdx.x * 4;
  for (int i = tid; i < 1152; i += 256) s_p[i] = pillars[pb * 288 + i];
  float w[9];
#pragma unroll
  for (int d = 0; d < 9; ++d) w[d] = lin_w[c * 9 + d];
  float bl = lin_b[c];
  float sc = ss[c], sh = ss[c + 64];
  __syncthreads();
  const float* pp = &s_p[pe * 288];
  float m = -1e30f;
#pragma unroll 4
  for (int n = 0; n < 32; ++n) {
    float y = bl;
#pragma unroll
    for (int d = 0; d < 9; ++d) y += pp[n * 9 + d] * w[d];
    float v = fmaxf(y * sc + sh, 0.f);
    m = fmaxf(m, v);
  }
  feats[(pb + pe) * 64 + c] = m;
}

// ------------------------------------------------------------------
// Scatter into padded bf16 HWC canvas (numpy last-write-wins)
// ------------------------------------------------------------------

__global__ void scatter_winner(const int* __restrict__ coords, int* __restrict__ winner,
                               int P) {
  int p = blockIdx.x * 256 + threadIdx.x;
  if (p >= P) return;
  int y = coords[p * 3 + 1], x = coords[p * 3 + 2];
  if (y >= 0 && y < 666 && x >= 0 && x < 666) atomicMax(&winner[y * 666 + x], p);
}

__global__ void scatter_img(const int* __restrict__ coords, const int* __restrict__ winner,
                            const float* __restrict__ feats, ushort_t* __restrict__ img,
                            int P, int PW) {
  int idx = blockIdx.x * 256 + threadIdx.x;
  int p = idx >> 6, c = idx & 63;
  if (p >= P) return;
  int y = coords[p * 3 + 1], x = coords[p * 3 + 2];
  if (y >= 0 && y < 666 && x >= 0 && x < 666) {
    if (winner[y * 666 + x] == p)
      img[((size_t)(y + 1) * PW + (x + 1)) * 64 + c] = f2bf(feats[p * 64 + c]);
  }
}

// ------------------------------------------------------------------
// Weight prep: OIHW fp32 -> fragment-ordered bf16 (Kc=32 layout)
// layout: [cc32][pos][s(2)][ntg][lane 64][8]
//   lane l: n = ntg*32 + (l&31); c = cc*32 + s*16 + (l>>5)*8 + j
// ------------------------------------------------------------------

__global__ void prep_w(const float* __restrict__ w, ushort_t* __restrict__ w2, int C,
                       int N, int Ntg, int chunks) {
  int u = blockIdx.x * 256 + threadIdx.x;
  int total = chunks * 9 * 2 * Ntg * 64;
  if (u >= total) return;
  int l = u & 63;
  int g = u >> 6;
  int ntg = g % Ntg;
  int g2 = g / Ntg;
  int s = g2 & 1;
  int g3 = g2 >> 1;
  int pos = g3 % 9;
  int cc = g3 / 9;
  int n = ntg * 32 + (l & 31);
  int c0 = cc * 32 + s * 16 + (l >> 5) * 8;
  ushort_t o8[8];
#pragma unroll
  for (int j = 0; j < 8; ++j) {
    int c = c0 + j;
    float v = (n < N && c < C) ? w[((size_t)n * C + c) * 9 + pos] : 0.f;
    o8[j] = f2bf(v);
  }
  *(uint4*)&w2[(size_t)u * 8] = *(const uint4*)o8;
}

// merged heads: n<21 -> hb_w, 21..23 -> hc_w, >=24 -> 0.  C=256, Ntg=1, chunks=8
__global__ void prep_w_head(const float* __restrict__ hb, const float* __restrict__ hc,
                            ushort_t* __restrict__ w2) {
  int u = blockIdx.x * 256 + threadIdx.x;
  int total = 8 * 9 * 2 * 64;
  if (u >= total) return;
  int l = u & 63;
  int g = u >> 6;
  int s = g & 1;
  int g3 = g >> 1;
  int pos = g3 % 9;
  int cc = g3 / 9;
  int n = l & 31;
  int c0 = cc * 32 + s * 16 + (l >> 5) * 8;
  ushort_t o8[8];
#pragma unroll
  for (int j = 0; j < 8; ++j) {
    int c = c0 + j;
    float v = 0.f;
    if (n < 21) v = hb[((size_t)n * 256 + c) * 9 + pos];
    else if (n < 24) v = hc[((size_t)(n - 21) * 256 + c) * 9 + pos];
    o8[j] = f2bf(v);
  }
  *(uint4*)&w2[(size_t)u * 8] = *(const uint4*)o8;
}

// ------------------------------------------------------------------
// Implicit-GEMM 3x3 conv via v_mfma_f32_32x32x16_bf16.
// Block = WAVES waves. Tile 64 px x WAVES rows, NT*32 oc per block.
// K chunked by 32 ch; stage input (WAVES+2)x66x32 (xor-swizzled) + weights.
// HEAD: blockIdx.z = K-split, atomic epilogue.  STATS: fused BN stats.
// ------------------------------------------------------------------

template <int NT, int WAVES, bool HEAD, bool STATS>
__global__ __launch_bounds__(WAVES * 64, WAVES == 8 ? 4 : 3) void conv_mfma(
    const ushort_t* __restrict__ in, const ushort_t* __restrict__ w2,
    const float* __restrict__ bias, const float* __restrict__ bias2,
    ushort_t* __restrict__ obf, float* __restrict__ oba, float* __restrict__ obb,
    float* __restrict__ statacc, int PW, int W, int H, int C, int nchunks, int Ntg) {
  constexpr int NTHREADS = WAVES * 64;
  __shared__ ushort_t s_in[(WAVES + 2) * 66 * 32];
  __shared__ ushort_t s_w[9 * 2 * NT * 512];
  const int tid = threadIdx.x;
  const int lane = tid & 63, wv = tid >> 6;
  const int lc = lane & 31, lh = lane >> 5;
  const int x0 = blockIdx.x * 64, y0 = blockIdx.y * WAVES;
  const int z = blockIdx.z;
  const int cc0 = HEAD ? z * nchunks : 0;
  const int z_oc = HEAD ? 0 : z;

  // per-lane A-address precompute
  int pc[2][2][3];
#pragma unroll
  for (int s = 0; s < 2; ++s)
#pragma unroll
    for (int Mt = 0; Mt < 2; ++Mt)
#pragma unroll
      for (int kx = 0; kx < 3; ++kx) {
        int col = Mt * 32 + kx + lc;
        int q = (2 * s + lh) ^ ((col >> 1) & 3);
        pc[s][Mt][kx] = col * 32 + q * 8;
      }

  float bv[NT];
#pragma unroll
  for (int nt = 0; nt < NT; ++nt) {
    if (HEAD) {
      bv[nt] = (z == 0) ? (lc < 21 ? bias[lc] : (lc < 24 ? bias2[lc - 21] : 0.f)) : 0.f;
    } else {
      bv[nt] = bias[(z * NT + nt) * 32 + lc];
    }
  }
  float16 acc[2][NT];
#pragma unroll
  for (int Mt = 0; Mt < 2; ++Mt)
#pragma unroll
    for (int nt = 0; nt < NT; ++nt)
#pragma unroll
      for (int r = 0; r < 16; ++r) acc[Mt][nt][r] = bv[nt];

  const ushort_t* inbase = in + ((size_t)y0 * PW + x0) * C;
  for (int cc = 0; cc < nchunks; ++cc) {
    const int ccg = cc0 + cc;
    __syncthreads();
    // stage input chunk: (WAVES+2) rows x 66 cols x 4 groups of 8ch (16 B units)
    for (int u = tid; u < (WAVES + 2) * 264; u += NTHREADS) {
      int r = u / 264;
      int sr = u - r * 264;
      int col = sr >> 2, f = sr & 3;
      int g = f ^ ((col >> 1) & 3);
      const ushort_t* src = inbase + ((size_t)r * PW + col) * C + ccg * 32 + g * 8;
      *(uint4*)&s_in[(r * 66 + col) * 32 + f * 8] = *(const uint4*)src;
    }
    // stage weight slice: [pos*2+s][nt] x 64 lanes x 16 B
    const int NW = NT * 1152;
    for (int u = tid; u < NW; u += NTHREADS) {
      int l16 = u & 63, grp = u >> 6;
      int nt = grp % NT, ps = grp / NT;
      const ushort_t* src =
          w2 + ((size_t)((ccg * 18 + ps) * Ntg + z_oc * NT + nt) * 64 + l16) * 8;
      *(uint4*)&s_w[(size_t)u * 8] = *(const uint4*)src;
    }
    __syncthreads();
#pragma unroll
    for (int ky = 0; ky < 3; ++ky) {
      int rowoff = (wv + ky) * (66 * 32);
#pragma unroll
      for (int kx = 0; kx < 3; ++kx) {
        const int pos = ky * 3 + kx;
#pragma unroll
        for (int s = 0; s < 2; ++s) {
          short8 Bf[NT];
#pragma unroll
          for (int nt = 0; nt < NT; ++nt)
            Bf[nt] = *(const short8*)&s_w[((pos * 2 + s) * NT + nt) * 512 + lane * 8];
#pragma unroll
          for (int Mt = 0; Mt < 2; ++Mt) {
            short8 Af = *(const short8*)&s_in[rowoff + pc[s][Mt][kx]];
#pragma unroll
            for (int nt = 0; nt < NT; ++nt)
              acc[Mt][nt] =
                  __builtin_amdgcn_mfma_f32_32x32x16_bf16(Af, Bf[nt], acc[Mt][nt], 0, 0, 0);
          }
        }
      }
    }
  }

  // ---- epilogue ----
  const int y = y0 + wv;
  const bool yok = (y < H);
  if (HEAD) {
    if (yok) {
#pragma unroll
      for (int Mt = 0; Mt < 2; ++Mt)
#pragma unroll
        for (int r = 0; r < 16; ++r) {
          int m = (r & 3) + 8 * (r >> 2) + 4 * lh;
          int x = x0 + Mt * 32 + m;
          if (x < W) {
            size_t sp = (size_t)y * W + x;
            float v = acc[Mt][0][r];
            if (lc < 21) atomicAdd(&oba[(size_t)lc * (size_t)(H * W) + sp], v);
            else if (lc < 24) atomicAdd(&obb[(size_t)(lc - 21) * (size_t)(H * W) + sp], v);
          }
        }
    }
    return;
  }

  const int Ntot = Ntg * 32;
  if (yok) {
#pragma unroll
    for (int Mt = 0; Mt < 2; ++Mt)
#pragma unroll
      for (int r = 0; r < 16; ++r) {
        int m = (r & 3) + 8 * (r >> 2) + 4 * lh;
        int x = x0 + Mt * 32 + m;
        if (x < W) {
          size_t sp = (size_t)y * W + x;
#pragma unroll
          for (int nt = 0; nt < NT; ++nt) {
            int oc = (z * NT + nt) * 32 + lc;
            obf[sp * Ntot + oc] = f2bf(acc[Mt][nt][r]);
          }
        }
      }
  }

  if (STATS) {
    float s1[NT], s2[NT];
#pragma unroll
    for (int nt = 0; nt < NT; ++nt) { s1[nt] = 0.f; s2[nt] = 0.f; }
    if (yok) {
#pragma unroll
      for (int Mt = 0; Mt < 2; ++Mt)
#pragma unroll
        for (int r = 0; r < 16; ++r) {
          int m = (r & 3) + 8 * (r >> 2) + 4 * lh;
          int x = x0 + Mt * 32 + m;
          if (x < W) {
#pragma unroll
            for (int nt = 0; nt < NT; ++nt) {
              float v = acc[Mt][nt][r];
              s1[nt] += v;
              s2[nt] += v * v;
            }
          }
        }
    }
#pragma unroll
    for (int nt = 0; nt < NT; ++nt) {
      s1[nt] += __shfl_xor(s1[nt], 32);
      s2[nt] += __shfl_xor(s2[nt], 32);
    }
    __syncthreads();  // all MFMA LDS reads done; reuse s_in as fp32 scratch
    float* red = (float*)s_in;
    if (lh == 0) {
#pragma unroll
      for (int nt = 0; nt < NT; ++nt) {
        red[(wv * NT + nt) * 32 + lc] = s1[nt];
        red[WAVES * NT * 32 + (wv * NT + nt) * 32 + lc] = s2[nt];
      }
    }
    __syncthreads();
    if (wv == 0 && lh == 0) {
#pragma unroll
      for (int nt = 0; nt < NT; ++nt) {
        float a = 0.f, b = 0.f;
#pragma unroll
        for (int w8 = 0; w8 < WAVES; ++w8) {
          a += red[(w8 * NT + nt) * 32 + lc];
          b += red[WAVES * NT * 32 + (w8 * NT + nt) * 32 + lc];
        }
        int ch = (z * NT + nt) * 32 + lc;
        atomicAdd(&statacc[ch], a);
        atomicAdd(&statacc[ch + 256], b);
      }
    }
  }
}

// ------------------------------------------------------------------
// Fused BN-finalize + elementwise (4 channels / thread, natural order).
// ------------------------------------------------------------------

__device__ __forceinline__ float bnrl(ushort_t u, float sc, float sh) {
  return fmaxf(bf2f(u) * sc + sh, 0.f);
}

__device__ __forceinline__ void bn_coefs(const float* acc, const float* g,
                                         const float* b, int c, float invN, float4& sc,
                                         float4& sh) {
  float4 s1 = *(const float4*)&acc[c];
  float4 s2 = *(const float4*)&acc[c + 256];
  float4 gv = *(const float4*)&g[c];
  float4 bv = *(const float4*)&b[c];
  float m, v;
  m = s1.x * invN; v = fmaxf(s2.x * invN - m * m, 0.f);
  sc.x = gv.x * rsqrtf(v + BN_EPS); sh.x = bv.x - m * sc.x;
  m = s1.y * invN; v = fmaxf(s2.y * invN - m * m, 0.f);
  sc.y = gv.y * rsqrtf(v + BN_EPS); sh.y = bv.y - m * sc.y;
  m = s1.z * invN; v = fmaxf(s2.z * invN - m * m, 0.f);
  sc.z = gv.z * rsqrtf(v + BN_EPS); sh.z = bv.z - m * sc.z;
  m = s1.w * invN; v = fmaxf(s2.w * invN - m * m, 0.f);
  sc.w = gv.w * rsqrtf(v + BN_EPS); sh.w = bv.w - m * sc.w;
}

// BN+relu+2x2pool from bf16 HWC (Wi wide) into padded bf16 HWC (PWo pitch)
__global__ __launch_bounds__(256) void bn_relu_pool_pad4(
    const ushort_t* __restrict__ in, const float* __restrict__ acc,
    const float* __restrict__ g, const float* __restrict__ b, float invN,
    ushort_t* __restrict__ out, int Wi, int OW, int OH, int C, int cshift2, int PWo) {
  int idx = blockIdx.x * 256 + threadIdx.x;
  int total = OH * OW * (C >> 2);
  if (idx >= total) return;
  int cq = idx & ((C >> 2) - 1);
  int p = idx >> cshift2;
  int ox = p % OW;
  int oy = p / OW;
  int c = cq << 2;
  float4 scv, shv;
  bn_coefs(acc, g, b, c, invN, scv, shv);
  const ushort_t* ip = in + ((size_t)(2 * oy) * Wi + 2 * ox) * C + c;
  ushort4 a0 = *(const ushort4*)(ip);
  ushort4 a1 = *(const ushort4*)(ip + C);
  ushort4 a2 = *(const ushort4*)(ip + (size_t)Wi * C);
  ushort4 a3 = *(const ushort4*)(ip + (size_t)Wi * C + C);
  ushort4 o;
  o.x = f2bf(fmaxf(fmaxf(bnrl(a0.x, scv.x, shv.x), bnrl(a1.x, scv.x, shv.x)),
                   fmaxf(bnrl(a2.x, scv.x, shv.x), bnrl(a3.x, scv.x, shv.x))));
  o.y = f2bf(fmaxf(fmaxf(bnrl(a0.y, scv.y, shv.y), bnrl(a1.y, scv.y, shv.y)),
                   fmaxf(bnrl(a2.y, scv.y, shv.y), bnrl(a3.y, scv.y, shv.y))));
  o.z = f2bf(fmaxf(fmaxf(bnrl(a0.z, scv.z, shv.z), bnrl(a1.z, scv.z, shv.z)),
                   fmaxf(bnrl(a2.z, scv.z, shv.z), bnrl(a3.z, scv.z, shv.z))));
  o.w = f2bf(fmaxf(fmaxf(bnrl(a0.w, scv.w, shv.w), bnrl(a1.w, scv.w, shv.w)),
                   fmaxf(bnrl(a2.w, scv.w, shv.w), bnrl(a3.w, scv.w, shv.w))));
  *(ushort4*)&out[((size_t)(oy + 1) * PWo + (ox + 1)) * C + c] = o;
}

// BN+relu (no pool) from bf16 HWC into padded bf16 HWC
__global__ __launch_bounds__(256) void bn_relu_pad4(
    const ushort_t* __restrict__ in, const float* __restrict__ acc,
    const float* __restrict__ g, const float* __restrict__ b, float invN,
    ushort_t* __restrict__ out, int Wi, int C, int cshift2, int PWo) {
  int idx = blockIdx.x * 256 + threadIdx.x;
  int total = Wi * Wi * (C >> 2);
  if (idx >= total) return;
  int cq = idx & ((C >> 2) - 1);
  int p = idx >> cshift2;
  int x = p % Wi;
  int y = p / Wi;
  int c = cq << 2;
  float4 scv, shv;
  bn_coefs(acc, g, b, c, invN, scv, shv);
  ushort4 a = *(const ushort4*)&in[(size_t)p * C + c];
  ushort4 o;
  o.x = f2bf(bnrl(a.x, scv.x, shv.x));
  o.y = f2bf(bnrl(a.y, scv.y, shv.y));
  o.z = f2bf(bnrl(a.z, scv.z, shv.z));
  o.w = f2bf(bnrl(a.w, scv.w, shv.w));
  *(ushort4*)&out[((size_t)(y + 1) * PWo + (x + 1)) * C + c] = o;
}

// ------------------------------------------------------------------

extern "C" void kernel_launch(void* const* d_in, const int* in_sizes, int n_in,
                              void* d_out, int out_size, void* d_ws, size_t ws_size,
                              hipStream_t stream) {
  (void)in_sizes; (void)n_in; (void)out_size; (void)ws_size;
  const float* pillars = (const float*)d_in[0];
  const int* coords = (const int*)d_in[1];
  const float* lin_w = (const float*)d_in[2];
  const float* lin_b = (const float*)d_in[3];
  const float* pfn_g = (const float*)d_in[4];
  const float* pfn_b = (const float*)d_in[5];
  const float* c1_w = (const float*)d_in[6];
  const float* c1_b = (const float*)d_in[7];
  const float* bn1_g = (const float*)d_in[8];
  const float* bn1_b = (const float*)d_in[9];
  const float* c2_w = (const float*)d_in[10];
  const float* c2_b = (const float*)d_in[11];
  const float* bn2_g = (const float*)d_in[12];
  const float* bn2_b = (const float*)d_in[13];
  const float* h1_w = (const float*)d_in[14];
  const float* h1_b = (const float*)d_in[15];
  const float* hbn_g = (const float*)d_in[16];
  const float* hbn_b = (const float*)d_in[17];
  const float* hb_w = (const float*)d_in[18];
  const float* hb_b = (const float*)d_in[19];
  const float* hc_w = (const float*)d_in[20];
  const float* hc_b = (const float*)d_in[21];
  float* out = (float*)d_out;

  // ---- workspace layout (bytes) ----
  char* ws = (char*)d_ws;
  float* pfn_acc = (float*)(ws + 0);         // 512 B
  float* pfn_ss  = (float*)(ws + 512);       // 512 B
  float* bn_acc1 = (float*)(ws + 1024);      // 2048 B
  float* bn_acc2 = (float*)(ws + 3072);      // 2048 B
  float* bn_acc3 = (float*)(ws + 5120);      // 2048 B
  int* winner    = (int*)(ws + 7168);        // 1774224 B
  float* feats   = (float*)(ws + 1781760);   // 5120000 B
  ushort_t* canvas = (ushort_t*)(ws + 6902272);     // 706x674x64   = 60899328 B
  ushort_t* c1out  = (ushort_t*)(ws + 67801600);    // 666x666x64   = 56775168 B
  ushort_t* c2in   = (ushort_t*)(ws + 124576768);   // 386x338x64   = 16699904 B
  ushort_t* c2out  = (ushort_t*)(ws + 141276672);   // 333x333x128  = 28387584 B
  ushort_t* h1in   = (ushort_t*)(ws + 169664256);   // 194x170x128  = 8442880 B
  ushort_t* h1out  = (ushort_t*)(ws + 178107136);   // 166x166x256  = 14108672 B
  ushort_t* hdin   = (ushort_t*)(ws + 192215808);   // 194x170x256  = 16885760 B
  ushort_t* w2c1   = (ushort_t*)(ws + 209101568);   // 73728 B
  ushort_t* w2c2   = (ushort_t*)(ws + 209175296);   // 147456 B
  ushort_t* w2h1   = (ushort_t*)(ws + 209322752);   // 589824 B
  ushort_t* w2hd   = (ushort_t*)(ws + 209912576);   // 147456 B

  const int HW3 = 166 * 166;

  // ---- upfront zero-init ----
  hipMemsetAsync(ws, 0, 7168, stream);  // pfn_acc/pfn_ss/bn_acc1-3
  hipMemsetAsync(winner, 0xFF, 1774224, stream);
  hipMemsetAsync(canvas, 0, 60899328, stream);
  hipMemsetAsync(c2in, 0, 16699904, stream);
  hipMemsetAsync(h1in, 0, 8442880, stream);
  hipMemsetAsync(hdin, 0, 16885760, stream);
  hipMemsetAsync(out, 0, (size_t)24 * HW3 * 4, stream);  // head accumulates via atomics

  // ---- weight prep (Kc=32 layout) ----
  prep_w<<<18, 256, 0, stream>>>(c1_w, w2c1, 64, 64, 2, 2);
  prep_w<<<36, 256, 0, stream>>>(c2_w, w2c2, 64, 128, 4, 2);
  prep_w<<<144, 256, 0, stream>>>(h1_w, w2h1, 128, 256, 8, 4);
  prep_w_head<<<36, 256, 0, stream>>>(hb_w, hc_w, w2hd);

  // ---- PFN ----
  pfn_stats<<<625, 256, 0, stream>>>(pillars, lin_w, lin_b, pfn_acc);
  pfn_finalize<<<1, 64, 0, stream>>>(pfn_acc, pfn_g, pfn_b, pfn_ss);
  pfn_feats<<<5000, 256, 0, stream>>>(pillars, lin_w, lin_b, pfn_ss, feats);

  // ---- scatter ----
  scatter_winner<<<(20000 + 255) / 256, 256, 0, stream>>>(coords, winner, 20000);
  scatter_img<<<5000, 256, 0, stream>>>(coords, winner, feats, canvas, 20000, 706);

  // ---- conv1: 666x666, 64->64, 8-wave blocks, 2 K-chunks (stats fused) ----
  conv_mfma<2, 8, false, true><<<dim3(11, 84, 1), 512, 0, stream>>>(
      canvas, w2c1, c1_b, nullptr, c1out, nullptr, nullptr, bn_acc1, 706, 666, 666, 64,
      2, 2);
  bn_relu_pool_pad4<<<(333 * 333 * 16 + 255) / 256, 256, 0, stream>>>(
      c1out, bn_acc1, bn1_g, bn1_b, 1.f / 443556.f, c2in, 666, 333, 333, 64, 4, 386);

  // ---- conv2: 333x333, 64->128, 8-wave blocks, 2 K-chunks (stats fused) ----
  conv_mfma<2, 8, false, true><<<dim3(6, 42, 2), 512, 0, stream>>>(
      c2in, w2c2, c2_b, nullptr, c2out, nullptr, nullptr, bn_acc2, 386, 333, 333, 64, 2,
      4);
  bn_relu_pool_pad4<<<(166 * 166 * 32 + 255) / 256, 256, 0, stream>>>(
      c2out, bn_acc2, bn2_g, bn2_b, 1.f / 110889.f, h1in, 333, 166, 166, 128, 5, 194);

  // ---- h1: 166x166, 128->256, NT=1 oc-split z=8, 4 K-chunks (stats fused) ----
  conv_mfma<1, 8, false, true><<<dim3(3, 21, 8), 512, 0, stream>>>(
      h1in, w2h1, h1_b, nullptr, h1out, nullptr, nullptr, bn_acc3, 194, 166, 166, 128, 4,
      8);
  bn_relu_pad4<<<(HW3 * 64 + 255) / 256, 256, 0, stream>>>(
      h1out, bn_acc3, hbn_g, hbn_b, 1.f / 27556.f, hdin, 166, 256, 6, 194);

  // ---- heads: 166x166, 256->(21+3), 4-wave blocks, K-split z=4, atomics ----
  conv_mfma<1, 4, true, false><<<dim3(3, 42, 4), 256, 0, stream>>>(
      hdin, w2hd, hb_b, hc_b, nullptr, out, out + (size_t)21 * HW3, nullptr, 194, 166,
      166, 256, 2, 1);
}

// Round 9
// 430.438 us; speedup vs baseline: 1.0887x; 1.0887x over previous
//
#include <hip/hip_runtime.h>
#include <hip/hip_bf16.h>
#include <cstdint>
#include <cstddef>

#define BN_EPS 1e-5f

typedef short short8 __attribute__((ext_vector_type(8)));
typedef float float16 __attribute__((ext_vector_type(16)));
typedef unsigned short ushort_t;

__device__ __forceinline__ float bf2f(ushort_t u) {
  return __uint_as_float(((unsigned int)u) << 16);
}
__device__ __forceinline__ ushort_t f2bf(float f) {
  unsigned int u = __float_as_uint(f);
  u += 0x7FFFu + ((u >> 16) & 1u);
  return (ushort_t)(u >> 16);
}

// ------------------------------------------------------------------
// PFN (fp32)
// ------------------------------------------------------------------

__global__ __launch_bounds__(256) void pfn_stats(
    const float* __restrict__ pillars, const float* __restrict__ lin_w,
    const float* __restrict__ lin_b, float* __restrict__ acc) {
  __shared__ float s_p[288];
  __shared__ float red[512];
  int tid = threadIdx.x;
  int c = tid & 63, rs = tid >> 6;
  float w[9];
#pragma unroll
  for (int d = 0; d < 9; ++d) w[d] = lin_w[c * 9 + d];
  float bl = lin_b[c];
  float s = 0.f, s2 = 0.f;
  long base_row = (long)blockIdx.x * 1024;
  for (int ch = 0; ch < 32; ++ch) {
    long crow = base_row + ch * 32;
    __syncthreads();
    for (int i = tid; i < 288; i += 256) s_p[i] = pillars[crow * 9 + i];
    __syncthreads();
#pragma unroll
    for (int k = 0; k < 8; ++k) {
      const float* pr = &s_p[(rs * 8 + k) * 9];
      float y = bl;
#pragma unroll
      for (int d = 0; d < 9; ++d) y += pr[d] * w[d];
      s += y;
      s2 += y * y;
    }
  }
  red[tid] = s;
  red[tid + 256] = s2;
  __syncthreads();
  if (rs == 0) {
    float ts = red[c] + red[c + 64] + red[c + 128] + red[c + 192];
    float t2 = red[256 + c] + red[256 + c + 64] + red[256 + c + 128] + red[256 + c + 192];
    atomicAdd(&acc[c], ts);
    atomicAdd(&acc[c + 64], t2);
  }
}

__global__ void pfn_finalize(const float* __restrict__ acc, const float* __restrict__ g,
                             const float* __restrict__ b, float* __restrict__ ss) {
  int c = threadIdx.x;  // 64 threads
  const float invN = 1.f / 640000.f;
  float m = acc[c] * invN;
  float v = acc[c + 64] * invN - m * m;
  v = fmaxf(v, 0.f);
  float inv = rsqrtf(v + BN_EPS);
  float sc = g[c] * inv;
  ss[c] = sc;
  ss[c + 64] = b[c] - m * sc;
}

__global__ __launch_bounds__(256) void pfn_feats(
    const float* __restrict__ pillars, const float* __restrict__ lin_w,
    const float* __restrict__ lin_b, const float* __restrict__ ss,
    float* __restrict__ feats) {
  __shared__ float s_p[1152];
  int tid = threadIdx.x;
  int c = tid & 63, pe = tid >> 6;
  long pb = (long)blockIdx.x * 4;
  for (int i = tid; i < 1152; i += 256) s_p[i] = pillars[pb * 288 + i];
  float w[9];
#pragma unroll
  for (int d = 0; d < 9; ++d) w[d] = lin_w[c * 9 + d];
  float bl = lin_b[c];
  float sc = ss[c], sh = ss[c + 64];
  __syncthreads();
  const float* pp = &s_p[pe * 288];
  float m = -1e30f;
#pragma unroll 4
  for (int n = 0; n < 32; ++n) {
    float y = bl;
#pragma unroll
    for (int d = 0; d < 9; ++d) y += pp[n * 9 + d] * w[d];
    float v = fmaxf(y * sc + sh, 0.f);
    m = fmaxf(m, v);
  }
  feats[(pb + pe) * 64 + c] = m;
}

// ------------------------------------------------------------------
// Scatter into padded bf16 HWC canvas (numpy last-write-wins)
// ------------------------------------------------------------------

__global__ void scatter_winner(const int* __restrict__ coords, int* __restrict__ winner,
                               int P) {
  int p = blockIdx.x * 256 + threadIdx.x;
  if (p >= P) return;
  int y = coords[p * 3 + 1], x = coords[p * 3 + 2];
  if (y >= 0 && y < 666 && x >= 0 && x < 666) atomicMax(&winner[y * 666 + x], p);
}

__global__ void scatter_img(const int* __restrict__ coords, const int* __restrict__ winner,
                            const float* __restrict__ feats, ushort_t* __restrict__ img,
                            int P, int PW) {
  int idx = blockIdx.x * 256 + threadIdx.x;
  int p = idx >> 6, c = idx & 63;
  if (p >= P) return;
  int y = coords[p * 3 + 1], x = coords[p * 3 + 2];
  if (y >= 0 && y < 666 && x >= 0 && x < 666) {
    if (winner[y * 666 + x] == p)
      img[((size_t)(y + 1) * PW + (x + 1)) * 64 + c] = f2bf(feats[p * 64 + c]);
  }
}

// ------------------------------------------------------------------
// Weight prep: OIHW fp32 -> fragment-ordered bf16 (Kc=32 layout)
// layout: [cc32][pos][s(2)][ntg][lane 64][8]
//   lane l: n = ntg*32 + (l&31); c = cc*32 + s*16 + (l>>5)*8 + j
// ------------------------------------------------------------------

__global__ void prep_w(const float* __restrict__ w, ushort_t* __restrict__ w2, int C,
                       int N, int Ntg, int chunks) {
  int u = blockIdx.x * 256 + threadIdx.x;
  int total = chunks * 9 * 2 * Ntg * 64;
  if (u >= total) return;
  int l = u & 63;
  int g = u >> 6;
  int ntg = g % Ntg;
  int g2 = g / Ntg;
  int s = g2 & 1;
  int g3 = g2 >> 1;
  int pos = g3 % 9;
  int cc = g3 / 9;
  int n = ntg * 32 + (l & 31);
  int c0 = cc * 32 + s * 16 + (l >> 5) * 8;
  ushort_t o8[8];
#pragma unroll
  for (int j = 0; j < 8; ++j) {
    int c = c0 + j;
    float v = (n < N && c < C) ? w[((size_t)n * C + c) * 9 + pos] : 0.f;
    o8[j] = f2bf(v);
  }
  *(uint4*)&w2[(size_t)u * 8] = *(const uint4*)o8;
}

// merged heads: n<21 -> hb_w, 21..23 -> hc_w, >=24 -> 0.  C=256, Ntg=1, chunks=8
__global__ void prep_w_head(const float* __restrict__ hb, const float* __restrict__ hc,
                            ushort_t* __restrict__ w2) {
  int u = blockIdx.x * 256 + threadIdx.x;
  int total = 8 * 9 * 2 * 64;
  if (u >= total) return;
  int l = u & 63;
  int g = u >> 6;
  int s = g & 1;
  int g3 = g >> 1;
  int pos = g3 % 9;
  int cc = g3 / 9;
  int n = l & 31;
  int c0 = cc * 32 + s * 16 + (l >> 5) * 8;
  ushort_t o8[8];
#pragma unroll
  for (int j = 0; j < 8; ++j) {
    int c = c0 + j;
    float v = 0.f;
    if (n < 21) v = hb[((size_t)n * 256 + c) * 9 + pos];
    else if (n < 24) v = hc[((size_t)(n - 21) * 256 + c) * 9 + pos];
    o8[j] = f2bf(v);
  }
  *(uint4*)&w2[(size_t)u * 8] = *(const uint4*)o8;
}

// ------------------------------------------------------------------
// Implicit-GEMM 3x3 conv via v_mfma_f32_32x32x16_bf16.
// Block = WAVES waves. Tile 64 px x WAVES rows, NT*32 oc per block.
// K chunked by 32 ch; stage input (WAVES+2)x66x32 (xor-swizzled) + weights.
// HEAD: blockIdx.z = K-split; coalesced fp32 partials into hpart (HWC x32).
// STATS: fused BN stats.
// ------------------------------------------------------------------

template <int NT, int WAVES, bool HEAD, bool STATS>
__global__ __launch_bounds__(WAVES * 64, WAVES == 8 ? 4 : 3) void conv_mfma(
    const ushort_t* __restrict__ in, const ushort_t* __restrict__ w2,
    const float* __restrict__ bias, const float* __restrict__ bias2,
    ushort_t* __restrict__ obf, float* __restrict__ hpart,
    float* __restrict__ statacc, int PW, int W, int H, int C, int nchunks, int Ntg) {
  constexpr int NTHREADS = WAVES * 64;
  __shared__ ushort_t s_in[(WAVES + 2) * 66 * 32];
  __shared__ ushort_t s_w[9 * 2 * NT * 512];
  const int tid = threadIdx.x;
  const int lane = tid & 63, wv = tid >> 6;
  const int lc = lane & 31, lh = lane >> 5;
  const int x0 = blockIdx.x * 64, y0 = blockIdx.y * WAVES;
  const int z = blockIdx.z;
  const int cc0 = HEAD ? z * nchunks : 0;
  const int z_oc = HEAD ? 0 : z;

  // per-lane A-address precompute
  int pc[2][2][3];
#pragma unroll
  for (int s = 0; s < 2; ++s)
#pragma unroll
    for (int Mt = 0; Mt < 2; ++Mt)
#pragma unroll
      for (int kx = 0; kx < 3; ++kx) {
        int col = Mt * 32 + kx + lc;
        int q = (2 * s + lh) ^ ((col >> 1) & 3);
        pc[s][Mt][kx] = col * 32 + q * 8;
      }

  float bv[NT];
#pragma unroll
  for (int nt = 0; nt < NT; ++nt) {
    if (HEAD) {
      bv[nt] = (z == 0) ? (lc < 21 ? bias[lc] : (lc < 24 ? bias2[lc - 21] : 0.f)) : 0.f;
    } else {
      bv[nt] = bias[(z * NT + nt) * 32 + lc];
    }
  }
  float16 acc[2][NT];
#pragma unroll
  for (int Mt = 0; Mt < 2; ++Mt)
#pragma unroll
    for (int nt = 0; nt < NT; ++nt)
#pragma unroll
      for (int r = 0; r < 16; ++r) acc[Mt][nt][r] = bv[nt];

  const ushort_t* inbase = in + ((size_t)y0 * PW + x0) * C;
  for (int cc = 0; cc < nchunks; ++cc) {
    const int ccg = cc0 + cc;
    __syncthreads();
    // stage input chunk: (WAVES+2) rows x 66 cols x 4 groups of 8ch (16 B units)
    for (int u = tid; u < (WAVES + 2) * 264; u += NTHREADS) {
      int r = u / 264;
      int sr = u - r * 264;
      int col = sr >> 2, f = sr & 3;
      int g = f ^ ((col >> 1) & 3);
      const ushort_t* src = inbase + ((size_t)r * PW + col) * C + ccg * 32 + g * 8;
      *(uint4*)&s_in[(r * 66 + col) * 32 + f * 8] = *(const uint4*)src;
    }
    // stage weight slice: [pos*2+s][nt] x 64 lanes x 16 B
    const int NW = NT * 1152;
    for (int u = tid; u < NW; u += NTHREADS) {
      int l16 = u & 63, grp = u >> 6;
      int nt = grp % NT, ps = grp / NT;
      const ushort_t* src =
          w2 + ((size_t)((ccg * 18 + ps) * Ntg + z_oc * NT + nt) * 64 + l16) * 8;
      *(uint4*)&s_w[(size_t)u * 8] = *(const uint4*)src;
    }
    __syncthreads();
#pragma unroll
    for (int ky = 0; ky < 3; ++ky) {
      int rowoff = (wv + ky) * (66 * 32);
#pragma unroll
      for (int kx = 0; kx < 3; ++kx) {
        const int pos = ky * 3 + kx;
#pragma unroll
        for (int s = 0; s < 2; ++s) {
          short8 Bf[NT];
#pragma unroll
          for (int nt = 0; nt < NT; ++nt)
            Bf[nt] = *(const short8*)&s_w[((pos * 2 + s) * NT + nt) * 512 + lane * 8];
#pragma unroll
          for (int Mt = 0; Mt < 2; ++Mt) {
            short8 Af = *(const short8*)&s_in[rowoff + pc[s][Mt][kx]];
#pragma unroll
            for (int nt = 0; nt < NT; ++nt)
              acc[Mt][nt] =
                  __builtin_amdgcn_mfma_f32_32x32x16_bf16(Af, Bf[nt], acc[Mt][nt], 0, 0, 0);
          }
        }
      }
    }
  }

  // ---- epilogue ----
  const int y = y0 + wv;
  const bool yok = (y < H);
  if (HEAD) {
    if (yok) {
      float* hp = hpart + (size_t)z * (size_t)(H * W) * 32;
#pragma unroll
      for (int Mt = 0; Mt < 2; ++Mt)
#pragma unroll
        for (int r = 0; r < 16; ++r) {
          int m = (r & 3) + 8 * (r >> 2) + 4 * lh;
          int x = x0 + Mt * 32 + m;
          if (x < W) {
            size_t sp = (size_t)y * W + x;
            hp[sp * 32 + lc] = acc[Mt][0][r];  // coalesced: lanes -> consecutive floats
          }
        }
    }
    return;
  }

  const int Ntot = Ntg * 32;
  if (yok) {
#pragma unroll
    for (int Mt = 0; Mt < 2; ++Mt)
#pragma unroll
      for (int r = 0; r < 16; ++r) {
        int m = (r & 3) + 8 * (r >> 2) + 4 * lh;
        int x = x0 + Mt * 32 + m;
        if (x < W) {
          size_t sp = (size_t)y * W + x;
#pragma unroll
          for (int nt = 0; nt < NT; ++nt) {
            int oc = (z * NT + nt) * 32 + lc;
            obf[sp * Ntot + oc] = f2bf(acc[Mt][nt][r]);
          }
        }
      }
  }

  if (STATS) {
    float s1[NT], s2[NT];
#pragma unroll
    for (int nt = 0; nt < NT; ++nt) { s1[nt] = 0.f; s2[nt] = 0.f; }
    if (yok) {
#pragma unroll
      for (int Mt = 0; Mt < 2; ++Mt)
#pragma unroll
        for (int r = 0; r < 16; ++r) {
          int m = (r & 3) + 8 * (r >> 2) + 4 * lh;
          int x = x0 + Mt * 32 + m;
          if (x < W) {
#pragma unroll
            for (int nt = 0; nt < NT; ++nt) {
              float v = acc[Mt][nt][r];
              s1[nt] += v;
              s2[nt] += v * v;
            }
          }
        }
    }
#pragma unroll
    for (int nt = 0; nt < NT; ++nt) {
      s1[nt] += __shfl_xor(s1[nt], 32);
      s2[nt] += __shfl_xor(s2[nt], 32);
    }
    __syncthreads();  // all MFMA LDS reads done; reuse s_in as fp32 scratch
    float* red = (float*)s_in;
    if (lh == 0) {
#pragma unroll
      for (int nt = 0; nt < NT; ++nt) {
        red[(wv * NT + nt) * 32 + lc] = s1[nt];
        red[WAVES * NT * 32 + (wv * NT + nt) * 32 + lc] = s2[nt];
      }
    }
    __syncthreads();
    if (wv == 0 && lh == 0) {
#pragma unroll
      for (int nt = 0; nt < NT; ++nt) {
        float a = 0.f, b = 0.f;
#pragma unroll
        for (int w8 = 0; w8 < WAVES; ++w8) {
          a += red[(w8 * NT + nt) * 32 + lc];
          b += red[WAVES * NT * 32 + (w8 * NT + nt) * 32 + lc];
        }
        int ch = (z * NT + nt) * 32 + lc;
        atomicAdd(&statacc[ch], a);
        atomicAdd(&statacc[ch + 256], b);
      }
    }
  }
}

// ------------------------------------------------------------------
// Head reduce: sum nz HWC(x32) fp32 partial slices, transpose through
// padded LDS, write 24 contiguous CHW channel planes into d_out.
// ------------------------------------------------------------------

__global__ __launch_bounds__(256) void head_reduce(const float* __restrict__ hp,
                                                   float* __restrict__ out, int HW,
                                                   int nz) {
  __shared__ float t[256 * 33];
  int tid = threadIdx.x;
  int sp0 = blockIdx.x * 256;
  int lim = (HW - sp0) * 32;  // valid elements in this block's window
#pragma unroll 4
  for (int i = 0; i < 32; ++i) {
    int e = i * 256 + tid;
    float s = 0.f;
    if (e < lim) {
      size_t gidx = (size_t)sp0 * 32 + e;
      for (int z = 0; z < nz; ++z) s += hp[(size_t)z * HW * 32 + gidx];
    }
    t[(e >> 5) * 33 + (e & 31)] = s;
  }
  __syncthreads();
  int sp = sp0 + tid;
  if (sp < HW) {
#pragma unroll
    for (int ch = 0; ch < 24; ++ch)
      out[(size_t)ch * HW + sp] = t[tid * 33 + ch];
  }
}

// ------------------------------------------------------------------
// Fused BN-finalize + elementwise (4 channels / thread, natural order).
// ------------------------------------------------------------------

__device__ __forceinline__ float bnrl(ushort_t u, float sc, float sh) {
  return fmaxf(bf2f(u) * sc + sh, 0.f);
}

__device__ __forceinline__ void bn_coefs(const float* acc, const float* g,
                                         const float* b, int c, float invN, float4& sc,
                                         float4& sh) {
  float4 s1 = *(const float4*)&acc[c];
  float4 s2 = *(const float4*)&acc[c + 256];
  float4 gv = *(const float4*)&g[c];
  float4 bv = *(const float4*)&b[c];
  float m, v;
  m = s1.x * invN; v = fmaxf(s2.x * invN - m * m, 0.f);
  sc.x = gv.x * rsqrtf(v + BN_EPS); sh.x = bv.x - m * sc.x;
  m = s1.y * invN; v = fmaxf(s2.y * invN - m * m, 0.f);
  sc.y = gv.y * rsqrtf(v + BN_EPS); sh.y = bv.y - m * sc.y;
  m = s1.z * invN; v = fmaxf(s2.z * invN - m * m, 0.f);
  sc.z = gv.z * rsqrtf(v + BN_EPS); sh.z = bv.z - m * sc.z;
  m = s1.w * invN; v = fmaxf(s2.w * invN - m * m, 0.f);
  sc.w = gv.w * rsqrtf(v + BN_EPS); sh.w = bv.w - m * sc.w;
}

// BN+relu+2x2pool from bf16 HWC (Wi wide) into padded bf16 HWC (PWo pitch)
__global__ __launch_bounds__(256) void bn_relu_pool_pad4(
    const ushort_t* __restrict__ in, const float* __restrict__ acc,
    const float* __restrict__ g, const float* __restrict__ b, float invN,
    ushort_t* __restrict__ out, int Wi, int OW, int OH, int C, int cshift2, int PWo) {
  int idx = blockIdx.x * 256 + threadIdx.x;
  int total = OH * OW * (C >> 2);
  if (idx >= total) return;
  int cq = idx & ((C >> 2) - 1);
  int p = idx >> cshift2;
  int ox = p % OW;
  int oy = p / OW;
  int c = cq << 2;
  float4 scv, shv;
  bn_coefs(acc, g, b, c, invN, scv, shv);
  const ushort_t* ip = in + ((size_t)(2 * oy) * Wi + 2 * ox) * C + c;
  ushort4 a0 = *(const ushort4*)(ip);
  ushort4 a1 = *(const ushort4*)(ip + C);
  ushort4 a2 = *(const ushort4*)(ip + (size_t)Wi * C);
  ushort4 a3 = *(const ushort4*)(ip + (size_t)Wi * C + C);
  ushort4 o;
  o.x = f2bf(fmaxf(fmaxf(bnrl(a0.x, scv.x, shv.x), bnrl(a1.x, scv.x, shv.x)),
                   fmaxf(bnrl(a2.x, scv.x, shv.x), bnrl(a3.x, scv.x, shv.x))));
  o.y = f2bf(fmaxf(fmaxf(bnrl(a0.y, scv.y, shv.y), bnrl(a1.y, scv.y, shv.y)),
                   fmaxf(bnrl(a2.y, scv.y, shv.y), bnrl(a3.y, scv.y, shv.y))));
  o.z = f2bf(fmaxf(fmaxf(bnrl(a0.z, scv.z, shv.z), bnrl(a1.z, scv.z, shv.z)),
                   fmaxf(bnrl(a2.z, scv.z, shv.z), bnrl(a3.z, scv.z, shv.z))));
  o.w = f2bf(fmaxf(fmaxf(bnrl(a0.w, scv.w, shv.w), bnrl(a1.w, scv.w, shv.w)),
                   fmaxf(bnrl(a2.w, scv.w, shv.w), bnrl(a3.w, scv.w, shv.w))));
  *(ushort4*)&out[((size_t)(oy + 1) * PWo + (ox + 1)) * C + c] = o;
}

// BN+relu (no pool) from bf16 HWC into padded bf16 HWC
__global__ __launch_bounds__(256) void bn_relu_pad4(
    const ushort_t* __restrict__ in, const float* __restrict__ acc,
    const float* __restrict__ g, const float* __restrict__ b, float invN,
    ushort_t* __restrict__ out, int Wi, int C, int cshift2, int PWo) {
  int idx = blockIdx.x * 256 + threadIdx.x;
  int total = Wi * Wi * (C >> 2);
  if (idx >= total) return;
  int cq = idx & ((C >> 2) - 1);
  int p = idx >> cshift2;
  int x = p % Wi;
  int y = p / Wi;
  int c = cq << 2;
  float4 scv, shv;
  bn_coefs(acc, g, b, c, invN, scv, shv);
  ushort4 a = *(const ushort4*)&in[(size_t)p * C + c];
  ushort4 o;
  o.x = f2bf(bnrl(a.x, scv.x, shv.x));
  o.y = f2bf(bnrl(a.y, scv.y, shv.y));
  o.z = f2bf(bnrl(a.z, scv.z, shv.z));
  o.w = f2bf(bnrl(a.w, scv.w, shv.w));
  *(ushort4*)&out[((size_t)(y + 1) * PWo + (x + 1)) * C + c] = o;
}

// ------------------------------------------------------------------

extern "C" void kernel_launch(void* const* d_in, const int* in_sizes, int n_in,
                              void* d_out, int out_size, void* d_ws, size_t ws_size,
                              hipStream_t stream) {
  (void)in_sizes; (void)n_in; (void)out_size; (void)ws_size;
  const float* pillars = (const float*)d_in[0];
  const int* coords = (const int*)d_in[1];
  const float* lin_w = (const float*)d_in[2];
  const float* lin_b = (const float*)d_in[3];
  const float* pfn_g = (const float*)d_in[4];
  const float* pfn_b = (const float*)d_in[5];
  const float* c1_w = (const float*)d_in[6];
  const float* c1_b = (const float*)d_in[7];
  const float* bn1_g = (const float*)d_in[8];
  const float* bn1_b = (const float*)d_in[9];
  const float* c2_w = (const float*)d_in[10];
  const float* c2_b = (const float*)d_in[11];
  const float* bn2_g = (const float*)d_in[12];
  const float* bn2_b = (const float*)d_in[13];
  const float* h1_w = (const float*)d_in[14];
  const float* h1_b = (const float*)d_in[15];
  const float* hbn_g = (const float*)d_in[16];
  const float* hbn_b = (const float*)d_in[17];
  const float* hb_w = (const float*)d_in[18];
  const float* hb_b = (const float*)d_in[19];
  const float* hc_w = (const float*)d_in[20];
  const float* hc_b = (const float*)d_in[21];
  float* out = (float*)d_out;

  // ---- workspace layout (bytes) ----
  char* ws = (char*)d_ws;
  float* pfn_acc = (float*)(ws + 0);         // 512 B
  float* pfn_ss  = (float*)(ws + 512);       // 512 B
  float* bn_acc1 = (float*)(ws + 1024);      // 2048 B
  float* bn_acc2 = (float*)(ws + 3072);      // 2048 B
  float* bn_acc3 = (float*)(ws + 5120);      // 2048 B
  int* winner    = (int*)(ws + 7168);        // 1774224 B
  float* feats   = (float*)(ws + 1781760);   // 5120000 B
  ushort_t* canvas = (ushort_t*)(ws + 6902272);     // 706x674x64   = 60899328 B
  ushort_t* c1out  = (ushort_t*)(ws + 67801600);    // 666x666x64   = 56775168 B
  ushort_t* c2in   = (ushort_t*)(ws + 124576768);   // 386x338x64   = 16699904 B
  ushort_t* c2out  = (ushort_t*)(ws + 141276672);   // 333x333x128  = 28387584 B
  ushort_t* h1in   = (ushort_t*)(ws + 169664256);   // 194x170x128  = 8442880 B
  ushort_t* h1out  = (ushort_t*)(ws + 178107136);   // 166x166x256  = 14108672 B
  ushort_t* hdin   = (ushort_t*)(ws + 192215808);   // 194x170x256  = 16885760 B
  ushort_t* w2c1   = (ushort_t*)(ws + 209101568);   // 73728 B
  ushort_t* w2c2   = (ushort_t*)(ws + 209175296);   // 147456 B
  ushort_t* w2h1   = (ushort_t*)(ws + 209322752);   // 589824 B
  ushort_t* w2hd   = (ushort_t*)(ws + 209912576);   // 147456 B
  float* hpart     = (float*)(ws + 210060032);      // 4x27556x32x4 = 14108672 B

  const int HW3 = 166 * 166;

  // ---- upfront zero-init ----
  hipMemsetAsync(ws, 0, 7168, stream);  // pfn_acc/pfn_ss/bn_acc1-3
  hipMemsetAsync(winner, 0xFF, 1774224, stream);
  hipMemsetAsync(canvas, 0, 60899328, stream);
  hipMemsetAsync(c2in, 0, 16699904, stream);
  hipMemsetAsync(h1in, 0, 8442880, stream);
  hipMemsetAsync(hdin, 0, 16885760, stream);

  // ---- weight prep (Kc=32 layout) ----
  prep_w<<<18, 256, 0, stream>>>(c1_w, w2c1, 64, 64, 2, 2);
  prep_w<<<36, 256, 0, stream>>>(c2_w, w2c2, 64, 128, 4, 2);
  prep_w<<<144, 256, 0, stream>>>(h1_w, w2h1, 128, 256, 8, 4);
  prep_w_head<<<36, 256, 0, stream>>>(hb_w, hc_w, w2hd);

  // ---- PFN ----
  pfn_stats<<<625, 256, 0, stream>>>(pillars, lin_w, lin_b, pfn_acc);
  pfn_finalize<<<1, 64, 0, stream>>>(pfn_acc, pfn_g, pfn_b, pfn_ss);
  pfn_feats<<<5000, 256, 0, stream>>>(pillars, lin_w, lin_b, pfn_ss, feats);

  // ---- scatter ----
  scatter_winner<<<(20000 + 255) / 256, 256, 0, stream>>>(coords, winner, 20000);
  scatter_img<<<5000, 256, 0, stream>>>(coords, winner, feats, canvas, 20000, 706);

  // ---- conv1: 666x666, 64->64, 8-wave blocks, 2 K-chunks (stats fused) ----
  conv_mfma<2, 8, false, true><<<dim3(11, 84, 1), 512, 0, stream>>>(
      canvas, w2c1, c1_b, nullptr, c1out, nullptr, bn_acc1, 706, 666, 666, 64, 2, 2);
  bn_relu_pool_pad4<<<(333 * 333 * 16 + 255) / 256, 256, 0, stream>>>(
      c1out, bn_acc1, bn1_g, bn1_b, 1.f / 443556.f, c2in, 666, 333, 333, 64, 4, 386);

  // ---- conv2: 333x333, 64->128, 8-wave blocks, 2 K-chunks (stats fused) ----
  conv_mfma<2, 8, false, true><<<dim3(6, 42, 2), 512, 0, stream>>>(
      c2in, w2c2, c2_b, nullptr, c2out, nullptr, bn_acc2, 386, 333, 333, 64, 2, 4);
  bn_relu_pool_pad4<<<(166 * 166 * 32 + 255) / 256, 256, 0, stream>>>(
      c2out, bn_acc2, bn2_g, bn2_b, 1.f / 110889.f, h1in, 333, 166, 166, 128, 5, 194);

  // ---- h1: 166x166, 128->256, NT=1 oc-split z=8, 4 K-chunks (stats fused) ----
  conv_mfma<1, 8, false, true><<<dim3(3, 21, 8), 512, 0, stream>>>(
      h1in, w2h1, h1_b, nullptr, h1out, nullptr, bn_acc3, 194, 166, 166, 128, 4, 8);
  bn_relu_pad4<<<(HW3 * 64 + 255) / 256, 256, 0, stream>>>(
      h1out, bn_acc3, hbn_g, hbn_b, 1.f / 27556.f, hdin, 166, 256, 6, 194);

  // ---- heads: 166x166, 256->(21+3), 4-wave, K-split z=4, coalesced partials ----
  conv_mfma<1, 4, true, false><<<dim3(3, 42, 4), 256, 0, stream>>>(
      hdin, w2hd, hb_b, hc_b, nullptr, hpart, nullptr, 194, 166, 166, 256, 2, 1);
  head_reduce<<<(HW3 + 255) / 256, 256, 0, stream>>>(hpart, out, HW3, 4);
}

// Round 10
// 406.480 us; speedup vs baseline: 1.1529x; 1.0589x over previous
//
#include <hip/hip_runtime.h>
#include <hip/hip_bf16.h>
#include <cstdint>
#include <cstddef>

#define BN_EPS 1e-5f

typedef short short8 __attribute__((ext_vector_type(8)));
typedef float float16 __attribute__((ext_vector_type(16)));
typedef unsigned short ushort_t;

__device__ __forceinline__ float bf2f(ushort_t u) {
  return __uint_as_float(((unsigned int)u) << 16);
}
__device__ __forceinline__ ushort_t f2bf(float f) {
  unsigned int u = __float_as_uint(f);
  u += 0x7FFFu + ((u >> 16) & 1u);
  return (ushort_t)(u >> 16);
}

// ------------------------------------------------------------------
// PFN (fp32)
// ------------------------------------------------------------------

__global__ __launch_bounds__(256) void pfn_stats(
    const float* __restrict__ pillars, const float* __restrict__ lin_w,
    const float* __restrict__ lin_b, float* __restrict__ acc) {
  __shared__ float s_p[288];
  __shared__ float red[512];
  int tid = threadIdx.x;
  int c = tid & 63, rs = tid >> 6;
  float w[9];
#pragma unroll
  for (int d = 0; d < 9; ++d) w[d] = lin_w[c * 9 + d];
  float bl = lin_b[c];
  float s = 0.f, s2 = 0.f;
  long base_row = (long)blockIdx.x * 1024;
  for (int ch = 0; ch < 32; ++ch) {
    long crow = base_row + ch * 32;
    __syncthreads();
    for (int i = tid; i < 288; i += 256) s_p[i] = pillars[crow * 9 + i];
    __syncthreads();
#pragma unroll
    for (int k = 0; k < 8; ++k) {
      const float* pr = &s_p[(rs * 8 + k) * 9];
      float y = bl;
#pragma unroll
      for (int d = 0; d < 9; ++d) y += pr[d] * w[d];
      s += y;
      s2 += y * y;
    }
  }
  red[tid] = s;
  red[tid + 256] = s2;
  __syncthreads();
  if (rs == 0) {
    float ts = red[c] + red[c + 64] + red[c + 128] + red[c + 192];
    float t2 = red[256 + c] + red[256 + c + 64] + red[256 + c + 128] + red[256 + c + 192];
    atomicAdd(&acc[c], ts);
    atomicAdd(&acc[c + 64], t2);
  }
}

__global__ void pfn_finalize(const float* __restrict__ acc, const float* __restrict__ g,
                             const float* __restrict__ b, float* __restrict__ ss) {
  int c = threadIdx.x;  // 64 threads
  const float invN = 1.f / 640000.f;
  float m = acc[c] * invN;
  float v = acc[c + 64] * invN - m * m;
  v = fmaxf(v, 0.f);
  float inv = rsqrtf(v + BN_EPS);
  float sc = g[c] * inv;
  ss[c] = sc;
  ss[c + 64] = b[c] - m * sc;
}

__global__ __launch_bounds__(256) void pfn_feats(
    const float* __restrict__ pillars, const float* __restrict__ lin_w,
    const float* __restrict__ lin_b, const float* __restrict__ ss,
    float* __restrict__ feats) {
  __shared__ float s_p[1152];
  int tid = threadIdx.x;
  int c = tid & 63, pe = tid >> 6;
  long pb = (long)blockIdx.x * 4;
  for (int i = tid; i < 1152; i += 256) s_p[i] = pillars[pb * 288 + i];
  float w[9];
#pragma unroll
  for (int d = 0; d < 9; ++d) w[d] = lin_w[c * 9 + d];
  float bl = lin_b[c];
  float sc = ss[c], sh = ss[c + 64];
  __syncthreads();
  const float* pp = &s_p[pe * 288];
  float m = -1e30f;
#pragma unroll 4
  for (int n = 0; n < 32; ++n) {
    float y = bl;
#pragma unroll
    for (int d = 0; d < 9; ++d) y += pp[n * 9 + d] * w[d];
    float v = fmaxf(y * sc + sh, 0.f);
    m = fmaxf(m, v);
  }
  feats[(pb + pe) * 64 + c] = m;
}

// ------------------------------------------------------------------
// Scatter into padded bf16 HWC canvas (numpy last-write-wins)
// ------------------------------------------------------------------

__global__ void scatter_winner(const int* __restrict__ coords, int* __restrict__ winner,
                               int P) {
  int p = blockIdx.x * 256 + threadIdx.x;
  if (p >= P) return;
  int y = coords[p * 3 + 1], x = coords[p * 3 + 2];
  if (y >= 0 && y < 666 && x >= 0 && x < 666) atomicMax(&winner[y * 666 + x], p);
}

__global__ void scatter_img(const int* __restrict__ coords, const int* __restrict__ winner,
                            const float* __restrict__ feats, ushort_t* __restrict__ img,
                            int P, int PW) {
  int idx = blockIdx.x * 256 + threadIdx.x;
  int p = idx >> 6, c = idx & 63;
  if (p >= P) return;
  int y = coords[p * 3 + 1], x = coords[p * 3 + 2];
  if (y >= 0 && y < 666 && x >= 0 && x < 666) {
    if (winner[y * 666 + x] == p)
      img[((size_t)(y + 1) * PW + (x + 1)) * 64 + c] = f2bf(feats[p * 64 + c]);
  }
}

// ------------------------------------------------------------------
// Weight prep: OIHW fp32 -> fragment-ordered bf16 (Kc=32 layout)
// layout: [cc32][pos][s(2)][ntg][lane 64][8]
//   lane l: n = ntg*32 + (l&31); c = cc*32 + s*16 + (l>>5)*8 + j
// ------------------------------------------------------------------

__global__ void prep_w(const float* __restrict__ w, ushort_t* __restrict__ w2, int C,
                       int N, int Ntg, int chunks) {
  int u = blockIdx.x * 256 + threadIdx.x;
  int total = chunks * 9 * 2 * Ntg * 64;
  if (u >= total) return;
  int l = u & 63;
  int g = u >> 6;
  int ntg = g % Ntg;
  int g2 = g / Ntg;
  int s = g2 & 1;
  int g3 = g2 >> 1;
  int pos = g3 % 9;
  int cc = g3 / 9;
  int n = ntg * 32 + (l & 31);
  int c0 = cc * 32 + s * 16 + (l >> 5) * 8;
  ushort_t o8[8];
#pragma unroll
  for (int j = 0; j < 8; ++j) {
    int c = c0 + j;
    float v = (n < N && c < C) ? w[((size_t)n * C + c) * 9 + pos] : 0.f;
    o8[j] = f2bf(v);
  }
  *(uint4*)&w2[(size_t)u * 8] = *(const uint4*)o8;
}

// merged heads: n<21 -> hb_w, 21..23 -> hc_w, >=24 -> 0.  C=256, Ntg=1, chunks=8
__global__ void prep_w_head(const float* __restrict__ hb, const float* __restrict__ hc,
                            ushort_t* __restrict__ w2) {
  int u = blockIdx.x * 256 + threadIdx.x;
  int total = 8 * 9 * 2 * 64;
  if (u >= total) return;
  int l = u & 63;
  int g = u >> 6;
  int s = g & 1;
  int g3 = g >> 1;
  int pos = g3 % 9;
  int cc = g3 / 9;
  int n = l & 31;
  int c0 = cc * 32 + s * 16 + (l >> 5) * 8;
  ushort_t o8[8];
#pragma unroll
  for (int j = 0; j < 8; ++j) {
    int c = c0 + j;
    float v = 0.f;
    if (n < 21) v = hb[((size_t)n * 256 + c) * 9 + pos];
    else if (n < 24) v = hc[((size_t)(n - 21) * 256 + c) * 9 + pos];
    o8[j] = f2bf(v);
  }
  *(uint4*)&w2[(size_t)u * 8] = *(const uint4*)o8;
}

// ------------------------------------------------------------------
// Implicit-GEMM 3x3 conv via v_mfma_f32_32x32x16_bf16.
// Block = WAVES waves. Tile 64 px x WAVES rows, NT*32 oc per block.
// K chunked by 32 ch; stage input (WAVES+2)x66x32 (xor-swizzled) + weights.
// HEAD: blockIdx.z = K-split; coalesced fp32 partials into hpart (HWC x32).
// STATS: fused BN stats (full-res, exact).
// POOL: fused raw 2x2 max-pool (valid since BN scale > 0 here -> monotone);
//       writes pooled RAW bf16 (W/2 x H/2, HWC), skips full-res write.
// ------------------------------------------------------------------

template <int NT, int WAVES, bool HEAD, bool STATS, bool POOL>
__global__ __launch_bounds__(WAVES * 64, WAVES == 8 ? 4 : 3) void conv_mfma(
    const ushort_t* __restrict__ in, const ushort_t* __restrict__ w2,
    const float* __restrict__ bias, const float* __restrict__ bias2,
    ushort_t* __restrict__ obf, float* __restrict__ hpart,
    float* __restrict__ statacc, int PW, int W, int H, int C, int nchunks, int Ntg) {
  constexpr int NTHREADS = WAVES * 64;
  __shared__ ushort_t s_in[(WAVES + 2) * 66 * 32];
  __shared__ ushort_t s_w[9 * 2 * NT * 512];
  const int tid = threadIdx.x;
  const int lane = tid & 63, wv = tid >> 6;
  const int lc = lane & 31, lh = lane >> 5;
  const int x0 = blockIdx.x * 64, y0 = blockIdx.y * WAVES;
  const int z = blockIdx.z;
  const int cc0 = HEAD ? z * nchunks : 0;
  const int z_oc = HEAD ? 0 : z;

  // per-lane A-address precompute
  int pc[2][2][3];
#pragma unroll
  for (int s = 0; s < 2; ++s)
#pragma unroll
    for (int Mt = 0; Mt < 2; ++Mt)
#pragma unroll
      for (int kx = 0; kx < 3; ++kx) {
        int col = Mt * 32 + kx + lc;
        int q = (2 * s + lh) ^ ((col >> 1) & 3);
        pc[s][Mt][kx] = col * 32 + q * 8;
      }

  float bv[NT];
#pragma unroll
  for (int nt = 0; nt < NT; ++nt) {
    if (HEAD) {
      bv[nt] = (z == 0) ? (lc < 21 ? bias[lc] : (lc < 24 ? bias2[lc - 21] : 0.f)) : 0.f;
    } else {
      bv[nt] = bias[(z * NT + nt) * 32 + lc];
    }
  }
  float16 acc[2][NT];
#pragma unroll
  for (int Mt = 0; Mt < 2; ++Mt)
#pragma unroll
    for (int nt = 0; nt < NT; ++nt)
#pragma unroll
      for (int r = 0; r < 16; ++r) acc[Mt][nt][r] = bv[nt];

  const ushort_t* inbase = in + ((size_t)y0 * PW + x0) * C;
  for (int cc = 0; cc < nchunks; ++cc) {
    const int ccg = cc0 + cc;
    __syncthreads();
    // stage input chunk: (WAVES+2) rows x 66 cols x 4 groups of 8ch (16 B units)
    for (int u = tid; u < (WAVES + 2) * 264; u += NTHREADS) {
      int r = u / 264;
      int sr = u - r * 264;
      int col = sr >> 2, f = sr & 3;
      int g = f ^ ((col >> 1) & 3);
      const ushort_t* src = inbase + ((size_t)r * PW + col) * C + ccg * 32 + g * 8;
      *(uint4*)&s_in[(r * 66 + col) * 32 + f * 8] = *(const uint4*)src;
    }
    // stage weight slice: [pos*2+s][nt] x 64 lanes x 16 B
    const int NW = NT * 1152;
    for (int u = tid; u < NW; u += NTHREADS) {
      int l16 = u & 63, grp = u >> 6;
      int nt = grp % NT, ps = grp / NT;
      const ushort_t* src =
          w2 + ((size_t)((ccg * 18 + ps) * Ntg + z_oc * NT + nt) * 64 + l16) * 8;
      *(uint4*)&s_w[(size_t)u * 8] = *(const uint4*)src;
    }
    __syncthreads();
#pragma unroll
    for (int ky = 0; ky < 3; ++ky) {
      int rowoff = (wv + ky) * (66 * 32);
#pragma unroll
      for (int kx = 0; kx < 3; ++kx) {
        const int pos = ky * 3 + kx;
#pragma unroll
        for (int s = 0; s < 2; ++s) {
          short8 Bf[NT];
#pragma unroll
          for (int nt = 0; nt < NT; ++nt)
            Bf[nt] = *(const short8*)&s_w[((pos * 2 + s) * NT + nt) * 512 + lane * 8];
#pragma unroll
          for (int Mt = 0; Mt < 2; ++Mt) {
            short8 Af = *(const short8*)&s_in[rowoff + pc[s][Mt][kx]];
#pragma unroll
            for (int nt = 0; nt < NT; ++nt)
              acc[Mt][nt] =
                  __builtin_amdgcn_mfma_f32_32x32x16_bf16(Af, Bf[nt], acc[Mt][nt], 0, 0, 0);
          }
        }
      }
    }
  }

  // ---- epilogue ----
  const int y = y0 + wv;
  const bool yok = (y < H);
  const int Ntot = Ntg * 32;

  if (HEAD) {
    if (yok) {
      float* hp = hpart + (size_t)z * (size_t)(H * W) * 32;
#pragma unroll
      for (int Mt = 0; Mt < 2; ++Mt)
#pragma unroll
        for (int r = 0; r < 16; ++r) {
          int m = (r & 3) + 8 * (r >> 2) + 4 * lh;
          int x = x0 + Mt * 32 + m;
          if (x < W) {
            size_t sp = (size_t)y * W + x;
            hp[sp * 32 + lc] = acc[Mt][0][r];  // coalesced
          }
        }
    }
    return;
  }

  if (!POOL) {
    if (yok) {
#pragma unroll
      for (int Mt = 0; Mt < 2; ++Mt)
#pragma unroll
        for (int r = 0; r < 16; ++r) {
          int m = (r & 3) + 8 * (r >> 2) + 4 * lh;
          int x = x0 + Mt * 32 + m;
          if (x < W) {
            size_t sp = (size_t)y * W + x;
#pragma unroll
            for (int nt = 0; nt < NT; ++nt) {
              int oc = (z * NT + nt) * 32 + lc;
              obf[sp * Ntot + oc] = f2bf(acc[Mt][nt][r]);
            }
          }
        }
    }
  }

  if (STATS) {
    float s1[NT], s2[NT];
#pragma unroll
    for (int nt = 0; nt < NT; ++nt) { s1[nt] = 0.f; s2[nt] = 0.f; }
    if (yok) {
#pragma unroll
      for (int Mt = 0; Mt < 2; ++Mt)
#pragma unroll
        for (int r = 0; r < 16; ++r) {
          int m = (r & 3) + 8 * (r >> 2) + 4 * lh;
          int x = x0 + Mt * 32 + m;
          if (x < W) {
#pragma unroll
            for (int nt = 0; nt < NT; ++nt) {
              float v = acc[Mt][nt][r];
              s1[nt] += v;
              s2[nt] += v * v;
            }
          }
        }
    }
#pragma unroll
    for (int nt = 0; nt < NT; ++nt) {
      s1[nt] += __shfl_xor(s1[nt], 32);
      s2[nt] += __shfl_xor(s2[nt], 32);
    }
    __syncthreads();  // all MFMA LDS reads done; reuse s_in as fp32 scratch
    float* red = (float*)s_in;
    if (lh == 0) {
#pragma unroll
      for (int nt = 0; nt < NT; ++nt) {
        red[(wv * NT + nt) * 32 + lc] = s1[nt];
        red[WAVES * NT * 32 + (wv * NT + nt) * 32 + lc] = s2[nt];
      }
    }
    __syncthreads();
    if (wv == 0 && lh == 0) {
#pragma unroll
      for (int nt = 0; nt < NT; ++nt) {
        float a = 0.f, b = 0.f;
#pragma unroll
        for (int w8 = 0; w8 < WAVES; ++w8) {
          a += red[(w8 * NT + nt) * 32 + lc];
          b += red[WAVES * NT * 32 + (w8 * NT + nt) * 32 + lc];
        }
        int ch = (z * NT + nt) * 32 + lc;
        atomicAdd(&statacc[ch], a);
        atomicAdd(&statacc[ch + 256], b);
      }
    }
  }

  if (POOL) {
    // raw 2x2 max pool. horizontal pairs are in-lane (r=2i, 2i+1);
    // vertical pairs are wave pairs (wv even, wv+1) via LDS.
    const int OWp = W >> 1, OHp = H >> 1;
    float hm[2][NT][8];
#pragma unroll
    for (int Mt = 0; Mt < 2; ++Mt)
#pragma unroll
      for (int nt = 0; nt < NT; ++nt)
#pragma unroll
        for (int i = 0; i < 8; ++i)
          hm[Mt][nt][i] = fmaxf(acc[Mt][nt][2 * i], acc[Mt][nt][2 * i + 1]);
    __syncthreads();
    float* pl = (float*)s_in;  // 4 slots x 2Mt x NT x 8 x 64 floats = 32 KB
    if (wv & 1) {
#pragma unroll
      for (int Mt = 0; Mt < 2; ++Mt)
#pragma unroll
        for (int nt = 0; nt < NT; ++nt)
#pragma unroll
          for (int i = 0; i < 8; ++i)
            pl[((((wv >> 1) * 2 + Mt) * NT + nt) * 8 + i) * 64 + lane] = hm[Mt][nt][i];
    }
    __syncthreads();
    if (!(wv & 1)) {
      int oy = (y0 + wv) >> 1;
      if (oy < OHp) {
#pragma unroll
        for (int Mt = 0; Mt < 2; ++Mt)
#pragma unroll
          for (int i = 0; i < 8; ++i) {
            int pxl = Mt * 16 + (i >> 1) * 4 + (i & 1) + 2 * lh;
            int ox = (x0 >> 1) + pxl;
            if (ox < OWp) {
#pragma unroll
              for (int nt = 0; nt < NT; ++nt) {
                float v = fmaxf(
                    hm[Mt][nt][i],
                    pl[((((wv >> 1) * 2 + Mt) * NT + nt) * 8 + i) * 64 + lane]);
                int oc = (z * NT + nt) * 32 + lc;
                obf[((size_t)oy * OWp + ox) * Ntot + oc] = f2bf(v);
              }
            }
          }
      }
    }
  }
}

// ------------------------------------------------------------------
// Head reduce: sum nz HWC(x32) fp32 partial slices, transpose through
// padded LDS, write 24 contiguous CHW channel planes into d_out.
// ------------------------------------------------------------------

__global__ __launch_bounds__(256) void head_reduce(const float* __restrict__ hp,
                                                   float* __restrict__ out, int HW,
                                                   int nz) {
  __shared__ float t[256 * 33];
  int tid = threadIdx.x;
  int sp0 = blockIdx.x * 256;
  int lim = (HW - sp0) * 32;
#pragma unroll 4
  for (int i = 0; i < 32; ++i) {
    int e = i * 256 + tid;
    float s = 0.f;
    if (e < lim) {
      size_t gidx = (size_t)sp0 * 32 + e;
      for (int z = 0; z < nz; ++z) s += hp[(size_t)z * HW * 32 + gidx];
    }
    t[(e >> 5) * 33 + (e & 31)] = s;
  }
  __syncthreads();
  int sp = sp0 + tid;
  if (sp < HW) {
#pragma unroll
    for (int ch = 0; ch < 24; ++ch)
      out[(size_t)ch * HW + sp] = t[tid * 33 + ch];
  }
}

// ------------------------------------------------------------------
// Fused BN-finalize + elementwise (4 channels / thread, natural order).
// ------------------------------------------------------------------

__device__ __forceinline__ float bnrl(ushort_t u, float sc, float sh) {
  return fmaxf(bf2f(u) * sc + sh, 0.f);
}

__device__ __forceinline__ void bn_coefs(const float* acc, const float* g,
                                         const float* b, int c, float invN, float4& sc,
                                         float4& sh) {
  float4 s1 = *(const float4*)&acc[c];
  float4 s2 = *(const float4*)&acc[c + 256];
  float4 gv = *(const float4*)&g[c];
  float4 bv = *(const float4*)&b[c];
  float m, v;
  m = s1.x * invN; v = fmaxf(s2.x * invN - m * m, 0.f);
  sc.x = gv.x * rsqrtf(v + BN_EPS); sh.x = bv.x - m * sc.x;
  m = s1.y * invN; v = fmaxf(s2.y * invN - m * m, 0.f);
  sc.y = gv.y * rsqrtf(v + BN_EPS); sh.y = bv.y - m * sc.y;
  m = s1.z * invN; v = fmaxf(s2.z * invN - m * m, 0.f);
  sc.z = gv.z * rsqrtf(v + BN_EPS); sh.z = bv.z - m * sc.z;
  m = s1.w * invN; v = fmaxf(s2.w * invN - m * m, 0.f);
  sc.w = gv.w * rsqrtf(v + BN_EPS); sh.w = bv.w - m * sc.w;
}

// BN+relu from bf16 HWC (Wi x Wi) into padded bf16 HWC (PWo pitch)
__global__ __launch_bounds__(256) void bn_relu_pad4(
    const ushort_t* __restrict__ in, const float* __restrict__ acc,
    const float* __restrict__ g, const float* __restrict__ b, float invN,
    ushort_t* __restrict__ out, int Wi, int C, int cshift2, int PWo) {
  int idx = blockIdx.x * 256 + threadIdx.x;
  int total = Wi * Wi * (C >> 2);
  if (idx >= total) return;
  int cq = idx & ((C >> 2) - 1);
  int p = idx >> cshift2;
  int x = p % Wi;
  int y = p / Wi;
  int c = cq << 2;
  float4 scv, shv;
  bn_coefs(acc, g, b, c, invN, scv, shv);
  ushort4 a = *(const ushort4*)&in[(size_t)p * C + c];
  ushort4 o;
  o.x = f2bf(bnrl(a.x, scv.x, shv.x));
  o.y = f2bf(bnrl(a.y, scv.y, shv.y));
  o.z = f2bf(bnrl(a.z, scv.z, shv.z));
  o.w = f2bf(bnrl(a.w, scv.w, shv.w));
  *(ushort4*)&out[((size_t)(y + 1) * PWo + (x + 1)) * C + c] = o;
}

// ------------------------------------------------------------------

extern "C" void kernel_launch(void* const* d_in, const int* in_sizes, int n_in,
                              void* d_out, int out_size, void* d_ws, size_t ws_size,
                              hipStream_t stream) {
  (void)in_sizes; (void)n_in; (void)out_size; (void)ws_size;
  const float* pillars = (const float*)d_in[0];
  const int* coords = (const int*)d_in[1];
  const float* lin_w = (const float*)d_in[2];
  const float* lin_b = (const float*)d_in[3];
  const float* pfn_g = (const float*)d_in[4];
  const float* pfn_b = (const float*)d_in[5];
  const float* c1_w = (const float*)d_in[6];
  const float* c1_b = (const float*)d_in[7];
  const float* bn1_g = (const float*)d_in[8];
  const float* bn1_b = (const float*)d_in[9];
  const float* c2_w = (const float*)d_in[10];
  const float* c2_b = (const float*)d_in[11];
  const float* bn2_g = (const float*)d_in[12];
  const float* bn2_b = (const float*)d_in[13];
  const float* h1_w = (const float*)d_in[14];
  const float* h1_b = (const float*)d_in[15];
  const float* hbn_g = (const float*)d_in[16];
  const float* hbn_b = (const float*)d_in[17];
  const float* hb_w = (const float*)d_in[18];
  const float* hb_b = (const float*)d_in[19];
  const float* hc_w = (const float*)d_in[20];
  const float* hc_b = (const float*)d_in[21];
  float* out = (float*)d_out;

  // ---- workspace layout (bytes) ----
  char* ws = (char*)d_ws;
  float* pfn_acc = (float*)(ws + 0);         // 512 B
  float* pfn_ss  = (float*)(ws + 512);       // 512 B
  float* bn_acc1 = (float*)(ws + 1024);      // 2048 B
  float* bn_acc2 = (float*)(ws + 3072);      // 2048 B
  float* bn_acc3 = (float*)(ws + 5120);      // 2048 B
  int* winner    = (int*)(ws + 7168);        // 1774224 B
  float* feats   = (float*)(ws + 1781760);   // 5120000 B
  ushort_t* canvas = (ushort_t*)(ws + 6902272);     // 706x674x64  = 60899328 B
  ushort_t* c2in   = (ushort_t*)(ws + 67801600);    // 386x338x64  = 16699904 B
  ushort_t* h1in   = (ushort_t*)(ws + 84501504);    // 194x170x128 = 8442880 B
  ushort_t* hdin   = (ushort_t*)(ws + 92944384);    // 194x170x256 = 16885760 B
  ushort_t* c1p    = (ushort_t*)(ws + 109830144);   // 333x333x64  = 14193792 B (pooled raw)
  ushort_t* c2p    = (ushort_t*)(ws + 124023936);   // 166x166x128 = 7054336 B (pooled raw)
  ushort_t* h1out  = (ushort_t*)(ws + 131078272);   // 166x166x256 = 14108672 B
  ushort_t* w2c1   = (ushort_t*)(ws + 145186944);   // 73728 B
  ushort_t* w2c2   = (ushort_t*)(ws + 145260672);   // 147456 B
  ushort_t* w2h1   = (ushort_t*)(ws + 145408128);   // 589824 B
  ushort_t* w2hd   = (ushort_t*)(ws + 145997952);   // 147456 B
  float* hpart     = (float*)(ws + 146145408);      // 4x27556x32x4 = 14108672 B

  const int HW3 = 166 * 166;

  // ---- upfront zero-init (c2in,h1in,hdin contiguous -> one memset) ----
  hipMemsetAsync(ws, 0, 7168, stream);
  hipMemsetAsync(winner, 0xFF, 1774224, stream);
  hipMemsetAsync(canvas, 0, 60899328, stream);
  hipMemsetAsync(c2in, 0, 16699904 + 8442880 + 16885760, stream);

  // ---- weight prep (Kc=32 layout) ----
  prep_w<<<18, 256, 0, stream>>>(c1_w, w2c1, 64, 64, 2, 2);
  prep_w<<<36, 256, 0, stream>>>(c2_w, w2c2, 64, 128, 4, 2);
  prep_w<<<144, 256, 0, stream>>>(h1_w, w2h1, 128, 256, 8, 4);
  prep_w_head<<<36, 256, 0, stream>>>(hb_w, hc_w, w2hd);

  // ---- PFN ----
  pfn_stats<<<625, 256, 0, stream>>>(pillars, lin_w, lin_b, pfn_acc);
  pfn_finalize<<<1, 64, 0, stream>>>(pfn_acc, pfn_g, pfn_b, pfn_ss);
  pfn_feats<<<5000, 256, 0, stream>>>(pillars, lin_w, lin_b, pfn_ss, feats);

  // ---- scatter ----
  scatter_winner<<<(20000 + 255) / 256, 256, 0, stream>>>(coords, winner, 20000);
  scatter_img<<<5000, 256, 0, stream>>>(coords, winner, feats, canvas, 20000, 706);

  // ---- conv1: 666x666, 64->64, stats + fused raw pool -> c1p (333x333x64) ----
  conv_mfma<2, 8, false, true, true><<<dim3(11, 84, 1), 512, 0, stream>>>(
      canvas, w2c1, c1_b, nullptr, c1p, nullptr, bn_acc1, 706, 666, 666, 64, 2, 2);
  bn_relu_pad4<<<(333 * 333 * 16 + 255) / 256, 256, 0, stream>>>(
      c1p, bn_acc1, bn1_g, bn1_b, 1.f / 443556.f, c2in, 333, 64, 4, 386);

  // ---- conv2: 333x333, 64->128, stats + fused raw pool -> c2p (166x166x128) ----
  conv_mfma<2, 8, false, true, true><<<dim3(6, 42, 2), 512, 0, stream>>>(
      c2in, w2c2, c2_b, nullptr, c2p, nullptr, bn_acc2, 386, 333, 333, 64, 2, 4);
  bn_relu_pad4<<<(166 * 166 * 32 + 255) / 256, 256, 0, stream>>>(
      c2p, bn_acc2, bn2_g, bn2_b, 1.f / 110889.f, h1in, 166, 128, 5, 194);

  // ---- h1: 166x166, 128->256, NT=1 oc-split z=8, 4 K-chunks (stats fused) ----
  conv_mfma<1, 8, false, true, false><<<dim3(3, 21, 8), 512, 0, stream>>>(
      h1in, w2h1, h1_b, nullptr, h1out, nullptr, bn_acc3, 194, 166, 166, 128, 4, 8);
  bn_relu_pad4<<<(HW3 * 64 + 255) / 256, 256, 0, stream>>>(
      h1out, bn_acc3, hbn_g, hbn_b, 1.f / 27556.f, hdin, 166, 256, 6, 194);

  // ---- heads: 166x166, 256->(21+3), 4-wave, K-split z=4, coalesced partials ----
  conv_mfma<1, 4, true, false, false><<<dim3(3, 42, 4), 256, 0, stream>>>(
      hdin, w2hd, hb_b, hc_b, nullptr, hpart, nullptr, 194, 166, 166, 256, 2, 1);
  head_reduce<<<(HW3 + 255) / 256, 256, 0, stream>>>(hpart, out, HW3, 4);
}

// Round 11
// 384.635 us; speedup vs baseline: 1.2184x; 1.0568x over previous
//
#include <hip/hip_runtime.h>
#include <hip/hip_bf16.h>
#include <cstdint>
#include <cstddef>

#define BN_EPS 1e-5f

typedef short short8 __attribute__((ext_vector_type(8)));
typedef float float16 __attribute__((ext_vector_type(16)));
typedef unsigned short ushort_t;

__device__ __forceinline__ float bf2f(ushort_t u) {
  return __uint_as_float(((unsigned int)u) << 16);
}
__device__ __forceinline__ ushort_t f2bf(float f) {
  unsigned int u = __float_as_uint(f);
  u += 0x7FFFu + ((u >> 16) & 1u);
  return (ushort_t)(u >> 16);
}

// ------------------------------------------------------------------
// PFN (fp32)
// ------------------------------------------------------------------

__global__ __launch_bounds__(256) void pfn_stats(
    const float* __restrict__ pillars, const float* __restrict__ lin_w,
    const float* __restrict__ lin_b, float* __restrict__ acc) {
  __shared__ float s_p[288];
  __shared__ float red[512];
  int tid = threadIdx.x;
  int c = tid & 63, rs = tid >> 6;
  float w[9];
#pragma unroll
  for (int d = 0; d < 9; ++d) w[d] = lin_w[c * 9 + d];
  float bl = lin_b[c];
  float s = 0.f, s2 = 0.f;
  long base_row = (long)blockIdx.x * 1024;
  for (int ch = 0; ch < 32; ++ch) {
    long crow = base_row + ch * 32;
    __syncthreads();
    for (int i = tid; i < 288; i += 256) s_p[i] = pillars[crow * 9 + i];
    __syncthreads();
#pragma unroll
    for (int k = 0; k < 8; ++k) {
      const float* pr = &s_p[(rs * 8 + k) * 9];
      float y = bl;
#pragma unroll
      for (int d = 0; d < 9; ++d) y += pr[d] * w[d];
      s += y;
      s2 += y * y;
    }
  }
  red[tid] = s;
  red[tid + 256] = s2;
  __syncthreads();
  if (rs == 0) {
    float ts = red[c] + red[c + 64] + red[c + 128] + red[c + 192];
    float t2 = red[256 + c] + red[256 + c + 64] + red[256 + c + 128] + red[256 + c + 192];
    atomicAdd(&acc[c], ts);
    atomicAdd(&acc[c + 64], t2);
  }
}

__global__ void pfn_finalize(const float* __restrict__ acc, const float* __restrict__ g,
                             const float* __restrict__ b, float* __restrict__ ss) {
  int c = threadIdx.x;  // 64 threads
  const float invN = 1.f / 640000.f;
  float m = acc[c] * invN;
  float v = acc[c + 64] * invN - m * m;
  v = fmaxf(v, 0.f);
  float inv = rsqrtf(v + BN_EPS);
  float sc = g[c] * inv;
  ss[c] = sc;
  ss[c + 64] = b[c] - m * sc;
}

__global__ __launch_bounds__(256) void pfn_feats(
    const float* __restrict__ pillars, const float* __restrict__ lin_w,
    const float* __restrict__ lin_b, const float* __restrict__ ss,
    float* __restrict__ feats) {
  __shared__ float s_p[1152];
  int tid = threadIdx.x;
  int c = tid & 63, pe = tid >> 6;
  long pb = (long)blockIdx.x * 4;
  for (int i = tid; i < 1152; i += 256) s_p[i] = pillars[pb * 288 + i];
  float w[9];
#pragma unroll
  for (int d = 0; d < 9; ++d) w[d] = lin_w[c * 9 + d];
  float bl = lin_b[c];
  float sc = ss[c], sh = ss[c + 64];
  __syncthreads();
  const float* pp = &s_p[pe * 288];
  float m = -1e30f;
#pragma unroll 4
  for (int n = 0; n < 32; ++n) {
    float y = bl;
#pragma unroll
    for (int d = 0; d < 9; ++d) y += pp[n * 9 + d] * w[d];
    float v = fmaxf(y * sc + sh, 0.f);
    m = fmaxf(m, v);
  }
  feats[(pb + pe) * 64 + c] = m;
}

// ------------------------------------------------------------------
// Scatter into padded bf16 HWC canvas (numpy last-write-wins)
// ------------------------------------------------------------------

__global__ void scatter_winner(const int* __restrict__ coords, int* __restrict__ winner,
                               int P) {
  int p = blockIdx.x * 256 + threadIdx.x;
  if (p >= P) return;
  int y = coords[p * 3 + 1], x = coords[p * 3 + 2];
  if (y >= 0 && y < 666 && x >= 0 && x < 666) atomicMax(&winner[y * 666 + x], p);
}

__global__ void scatter_img(const int* __restrict__ coords, const int* __restrict__ winner,
                            const float* __restrict__ feats, ushort_t* __restrict__ img,
                            int P, int PW) {
  int idx = blockIdx.x * 256 + threadIdx.x;
  int p = idx >> 6, c = idx & 63;
  if (p >= P) return;
  int y = coords[p * 3 + 1], x = coords[p * 3 + 2];
  if (y >= 0 && y < 666 && x >= 0 && x < 666) {
    if (winner[y * 666 + x] == p)
      img[((size_t)(y + 1) * PW + (x + 1)) * 64 + c] = f2bf(feats[p * 64 + c]);
  }
}

// ------------------------------------------------------------------
// Weight prep: OIHW fp32 -> fragment-ordered bf16 (Kc=32 layout)
// ------------------------------------------------------------------

__global__ void prep_w(const float* __restrict__ w, ushort_t* __restrict__ w2, int C,
                       int N, int Ntg, int chunks) {
  int u = blockIdx.x * 256 + threadIdx.x;
  int total = chunks * 9 * 2 * Ntg * 64;
  if (u >= total) return;
  int l = u & 63;
  int g = u >> 6;
  int ntg = g % Ntg;
  int g2 = g / Ntg;
  int s = g2 & 1;
  int g3 = g2 >> 1;
  int pos = g3 % 9;
  int cc = g3 / 9;
  int n = ntg * 32 + (l & 31);
  int c0 = cc * 32 + s * 16 + (l >> 5) * 8;
  ushort_t o8[8];
#pragma unroll
  for (int j = 0; j < 8; ++j) {
    int c = c0 + j;
    float v = (n < N && c < C) ? w[((size_t)n * C + c) * 9 + pos] : 0.f;
    o8[j] = f2bf(v);
  }
  *(uint4*)&w2[(size_t)u * 8] = *(const uint4*)o8;
}

// merged heads: n<21 -> hb_w, 21..23 -> hc_w, >=24 -> 0.  C=256, Ntg=1, chunks=8
__global__ void prep_w_head(const float* __restrict__ hb, const float* __restrict__ hc,
                            ushort_t* __restrict__ w2) {
  int u = blockIdx.x * 256 + threadIdx.x;
  int total = 8 * 9 * 2 * 64;
  if (u >= total) return;
  int l = u & 63;
  int g = u >> 6;
  int s = g & 1;
  int g3 = g >> 1;
  int pos = g3 % 9;
  int cc = g3 / 9;
  int n = l & 31;
  int c0 = cc * 32 + s * 16 + (l >> 5) * 8;
  ushort_t o8[8];
#pragma unroll
  for (int j = 0; j < 8; ++j) {
    int c = c0 + j;
    float v = 0.f;
    if (n < 21) v = hb[((size_t)n * 256 + c) * 9 + pos];
    else if (n < 24) v = hc[((size_t)(n - 21) * 256 + c) * 9 + pos];
    o8[j] = f2bf(v);
  }
  *(uint4*)&w2[(size_t)u * 8] = *(const uint4*)o8;
}

// ------------------------------------------------------------------
// BN coef publish: sc[c], sh[c] from stats accumulators
// ------------------------------------------------------------------

__global__ void bn_make_coefs(const float* __restrict__ acc, const float* __restrict__ g,
                              const float* __restrict__ b, float invN,
                              float* __restrict__ coef, int C) {
  int c = threadIdx.x;
  if (c >= C) return;
  float m = acc[c] * invN;
  float v = fmaxf(acc[c + 256] * invN - m * m, 0.f);
  float sc = g[c] * rsqrtf(v + BN_EPS);
  coef[c] = sc;
  coef[C + c] = b[c] - m * sc;
}

// ------------------------------------------------------------------
// Implicit-GEMM 3x3 conv via v_mfma_f32_32x32x16_bf16.
// Block = WAVES waves. Tile 64 px x WAVES rows, NT*32 oc per block.
// K chunked by 32 ch; stage input (WAVES+2)x66x32 (xor-swizzled) + weights.
// BNSTAGE: input is RAW unpadded HWC; staging applies relu(x*sc+sh) with
//   per-thread fixed channel-group (g = tid&3) and bounds-checked zero pad.
// HEAD: blockIdx.z = K-split; coalesced fp32 partials into hpart (HWC x32).
// STATS: fused BN stats (full-res, exact).
// POOL: fused raw 2x2 max-pool (valid: BN scale > 0 -> monotone).
// ------------------------------------------------------------------

template <int NT, int WAVES, bool HEAD, bool STATS, bool POOL, bool BNSTAGE>
__global__ __launch_bounds__(WAVES * 64, WAVES == 8 ? 4 : 3) void conv_mfma(
    const ushort_t* __restrict__ in, const ushort_t* __restrict__ w2,
    const float* __restrict__ bias, const float* __restrict__ bias2,
    const float* __restrict__ coef_in, ushort_t* __restrict__ obf,
    float* __restrict__ hpart, float* __restrict__ statacc, int PW, int W, int H, int C,
    int nchunks, int Ntg) {
  constexpr int NTHREADS = WAVES * 64;
  __shared__ ushort_t s_in[(WAVES + 2) * 66 * 32];
  __shared__ ushort_t s_w[9 * 2 * NT * 512];
  const int tid = threadIdx.x;
  const int lane = tid & 63, wv = tid >> 6;
  const int lc = lane & 31, lh = lane >> 5;
  const int x0 = blockIdx.x * 64, y0 = blockIdx.y * WAVES;
  const int z = blockIdx.z;
  const int cc0 = HEAD ? z * nchunks : 0;
  const int z_oc = HEAD ? 0 : z;

  // per-lane A-address precompute
  int pc[2][2][3];
#pragma unroll
  for (int s = 0; s < 2; ++s)
#pragma unroll
    for (int Mt = 0; Mt < 2; ++Mt)
#pragma unroll
      for (int kx = 0; kx < 3; ++kx) {
        int col = Mt * 32 + kx + lc;
        int q = (2 * s + lh) ^ ((col >> 1) & 3);
        pc[s][Mt][kx] = col * 32 + q * 8;
      }

  float bv[NT];
#pragma unroll
  for (int nt = 0; nt < NT; ++nt) {
    if (HEAD) {
      bv[nt] = (z == 0) ? (lc < 21 ? bias[lc] : (lc < 24 ? bias2[lc - 21] : 0.f)) : 0.f;
    } else {
      bv[nt] = bias[(z * NT + nt) * 32 + lc];
    }
  }
  float16 acc[2][NT];
#pragma unroll
  for (int Mt = 0; Mt < 2; ++Mt)
#pragma unroll
    for (int nt = 0; nt < NT; ++nt)
#pragma unroll
      for (int r = 0; r < 16; ++r) acc[Mt][nt][r] = bv[nt];

  const ushort_t* inbase = in + ((size_t)y0 * PW + x0) * C;  // PAD mode only
  const int sg = tid & 3;        // BNSTAGE: fixed channel group per thread
  const int tpos = tid >> 2;
  constexpr int TPOS = NTHREADS / 4;

  for (int cc = 0; cc < nchunks; ++cc) {
    const int ccg = cc0 + cc;
    __syncthreads();
    if (BNSTAGE) {
      // load this chunk's 8 coefs for my channel group
      float sc8[8], sh8[8];
      {
        int ch = ccg * 32 + sg * 8;
        float4 a0 = *(const float4*)&coef_in[ch];
        float4 a1 = *(const float4*)&coef_in[ch + 4];
        float4 b0 = *(const float4*)&coef_in[C + ch];
        float4 b1 = *(const float4*)&coef_in[C + ch + 4];
        sc8[0] = a0.x; sc8[1] = a0.y; sc8[2] = a0.z; sc8[3] = a0.w;
        sc8[4] = a1.x; sc8[5] = a1.y; sc8[6] = a1.z; sc8[7] = a1.w;
        sh8[0] = b0.x; sh8[1] = b0.y; sh8[2] = b0.z; sh8[3] = b0.w;
        sh8[4] = b1.x; sh8[5] = b1.y; sh8[6] = b1.z; sh8[7] = b1.w;
      }
      for (int p = tpos; p < (WAVES + 2) * 66; p += TPOS) {
        int r = p / 66, col = p - r * 66;
        int gy = y0 - 1 + r, gx = x0 - 1 + col;
        ushort_t v8[8] = {0, 0, 0, 0, 0, 0, 0, 0};
        if (gy >= 0 && gy < H && gx >= 0 && gx < W) {
          const ushort_t* src = in + ((size_t)gy * W + gx) * C + ccg * 32 + sg * 8;
          uint4 raw = *(const uint4*)src;
          const ushort_t* rp = (const ushort_t*)&raw;
#pragma unroll
          for (int j = 0; j < 8; ++j)
            v8[j] = f2bf(fmaxf(bf2f(rp[j]) * sc8[j] + sh8[j], 0.f));
        }
        int f = sg ^ ((col >> 1) & 3);
        *(uint4*)&s_in[(r * 66 + col) * 32 + f * 8] = *(const uint4*)v8;
      }
    } else {
      for (int u = tid; u < (WAVES + 2) * 264; u += NTHREADS) {
        int r = u / 264;
        int sr = u - r * 264;
        int col = sr >> 2, f = sr & 3;
        int g = f ^ ((col >> 1) & 3);
        const ushort_t* src = inbase + ((size_t)r * PW + col) * C + ccg * 32 + g * 8;
        *(uint4*)&s_in[(r * 66 + col) * 32 + f * 8] = *(const uint4*)src;
      }
    }
    // stage weight slice: [pos*2+s][nt] x 64 lanes x 16 B
    const int NW = NT * 1152;
    for (int u = tid; u < NW; u += NTHREADS) {
      int l16 = u & 63, grp = u >> 6;
      int nt = grp % NT, ps = grp / NT;
      const ushort_t* src =
          w2 + ((size_t)((ccg * 18 + ps) * Ntg + z_oc * NT + nt) * 64 + l16) * 8;
      *(uint4*)&s_w[(size_t)u * 8] = *(const uint4*)src;
    }
    __syncthreads();
#pragma unroll
    for (int ky = 0; ky < 3; ++ky) {
      int rowoff = (wv + ky) * (66 * 32);
#pragma unroll
      for (int kx = 0; kx < 3; ++kx) {
        const int pos = ky * 3 + kx;
#pragma unroll
        for (int s = 0; s < 2; ++s) {
          short8 Bf[NT];
#pragma unroll
          for (int nt = 0; nt < NT; ++nt)
            Bf[nt] = *(const short8*)&s_w[((pos * 2 + s) * NT + nt) * 512 + lane * 8];
#pragma unroll
          for (int Mt = 0; Mt < 2; ++Mt) {
            short8 Af = *(const short8*)&s_in[rowoff + pc[s][Mt][kx]];
#pragma unroll
            for (int nt = 0; nt < NT; ++nt)
              acc[Mt][nt] =
                  __builtin_amdgcn_mfma_f32_32x32x16_bf16(Af, Bf[nt], acc[Mt][nt], 0, 0, 0);
          }
        }
      }
    }
  }

  // ---- epilogue ----
  const int y = y0 + wv;
  const bool yok = (y < H);
  const int Ntot = Ntg * 32;

  if (HEAD) {
    if (yok) {
      float* hp = hpart + (size_t)z * (size_t)(H * W) * 32;
#pragma unroll
      for (int Mt = 0; Mt < 2; ++Mt)
#pragma unroll
        for (int r = 0; r < 16; ++r) {
          int m = (r & 3) + 8 * (r >> 2) + 4 * lh;
          int x = x0 + Mt * 32 + m;
          if (x < W) {
            size_t sp = (size_t)y * W + x;
            hp[sp * 32 + lc] = acc[Mt][0][r];  // coalesced
          }
        }
    }
    return;
  }

  if (!POOL) {
    if (yok) {
#pragma unroll
      for (int Mt = 0; Mt < 2; ++Mt)
#pragma unroll
        for (int r = 0; r < 16; ++r) {
          int m = (r & 3) + 8 * (r >> 2) + 4 * lh;
          int x = x0 + Mt * 32 + m;
          if (x < W) {
            size_t sp = (size_t)y * W + x;
#pragma unroll
            for (int nt = 0; nt < NT; ++nt) {
              int oc = (z * NT + nt) * 32 + lc;
              obf[sp * Ntot + oc] = f2bf(acc[Mt][nt][r]);
            }
          }
        }
    }
  }

  if (STATS) {
    float s1[NT], s2[NT];
#pragma unroll
    for (int nt = 0; nt < NT; ++nt) { s1[nt] = 0.f; s2[nt] = 0.f; }
    if (yok) {
#pragma unroll
      for (int Mt = 0; Mt < 2; ++Mt)
#pragma unroll
        for (int r = 0; r < 16; ++r) {
          int m = (r & 3) + 8 * (r >> 2) + 4 * lh;
          int x = x0 + Mt * 32 + m;
          if (x < W) {
#pragma unroll
            for (int nt = 0; nt < NT; ++nt) {
              float v = acc[Mt][nt][r];
              s1[nt] += v;
              s2[nt] += v * v;
            }
          }
        }
    }
#pragma unroll
    for (int nt = 0; nt < NT; ++nt) {
      s1[nt] += __shfl_xor(s1[nt], 32);
      s2[nt] += __shfl_xor(s2[nt], 32);
    }
    __syncthreads();  // all MFMA LDS reads done; reuse s_in as fp32 scratch
    float* red = (float*)s_in;
    if (lh == 0) {
#pragma unroll
      for (int nt = 0; nt < NT; ++nt) {
        red[(wv * NT + nt) * 32 + lc] = s1[nt];
        red[WAVES * NT * 32 + (wv * NT + nt) * 32 + lc] = s2[nt];
      }
    }
    __syncthreads();
    if (wv == 0 && lh == 0) {
#pragma unroll
      for (int nt = 0; nt < NT; ++nt) {
        float a = 0.f, b = 0.f;
#pragma unroll
        for (int w8 = 0; w8 < WAVES; ++w8) {
          a += red[(w8 * NT + nt) * 32 + lc];
          b += red[WAVES * NT * 32 + (w8 * NT + nt) * 32 + lc];
        }
        int ch = (z * NT + nt) * 32 + lc;
        atomicAdd(&statacc[ch], a);
        atomicAdd(&statacc[ch + 256], b);
      }
    }
  }

  if (POOL) {
    const int OWp = W >> 1, OHp = H >> 1;
    float hm[2][NT][8];
#pragma unroll
    for (int Mt = 0; Mt < 2; ++Mt)
#pragma unroll
      for (int nt = 0; nt < NT; ++nt)
#pragma unroll
        for (int i = 0; i < 8; ++i)
          hm[Mt][nt][i] = fmaxf(acc[Mt][nt][2 * i], acc[Mt][nt][2 * i + 1]);
    __syncthreads();
    float* pl = (float*)s_in;
    if (wv & 1) {
#pragma unroll
      for (int Mt = 0; Mt < 2; ++Mt)
#pragma unroll
        for (int nt = 0; nt < NT; ++nt)
#pragma unroll
          for (int i = 0; i < 8; ++i)
            pl[((((wv >> 1) * 2 + Mt) * NT + nt) * 8 + i) * 64 + lane] = hm[Mt][nt][i];
    }
    __syncthreads();
    if (!(wv & 1)) {
      int oy = (y0 + wv) >> 1;
      if (oy < OHp) {
#pragma unroll
        for (int Mt = 0; Mt < 2; ++Mt)
#pragma unroll
          for (int i = 0; i < 8; ++i) {
            int pxl = Mt * 16 + (i >> 1) * 4 + (i & 1) + 2 * lh;
            int ox = (x0 >> 1) + pxl;
            if (ox < OWp) {
#pragma unroll
              for (int nt = 0; nt < NT; ++nt) {
                float v = fmaxf(
                    hm[Mt][nt][i],
                    pl[((((wv >> 1) * 2 + Mt) * NT + nt) * 8 + i) * 64 + lane]);
                int oc = (z * NT + nt) * 32 + lc;
                obf[((size_t)oy * OWp + ox) * Ntot + oc] = f2bf(v);
              }
            }
          }
      }
    }
  }
}

// ------------------------------------------------------------------
// Head reduce: sum nz HWC(x32) fp32 partial slices, transpose through
// padded LDS, write 24 contiguous CHW channel planes into d_out.
// ------------------------------------------------------------------

__global__ __launch_bounds__(256) void head_reduce(const float* __restrict__ hp,
                                                   float* __restrict__ out, int HW,
                                                   int nz) {
  __shared__ float t[256 * 33];
  int tid = threadIdx.x;
  int sp0 = blockIdx.x * 256;
  int lim = (HW - sp0) * 32;
#pragma unroll 4
  for (int i = 0; i < 32; ++i) {
    int e = i * 256 + tid;
    float s = 0.f;
    if (e < lim) {
      size_t gidx = (size_t)sp0 * 32 + e;
      for (int z = 0; z < nz; ++z) s += hp[(size_t)z * HW * 32 + gidx];
    }
    t[(e >> 5) * 33 + (e & 31)] = s;
  }
  __syncthreads();
  int sp = sp0 + tid;
  if (sp < HW) {
#pragma unroll
    for (int ch = 0; ch < 24; ++ch)
      out[(size_t)ch * HW + sp] = t[tid * 33 + ch];
  }
}

// ------------------------------------------------------------------

extern "C" void kernel_launch(void* const* d_in, const int* in_sizes, int n_in,
                              void* d_out, int out_size, void* d_ws, size_t ws_size,
                              hipStream_t stream) {
  (void)in_sizes; (void)n_in; (void)out_size; (void)ws_size;
  const float* pillars = (const float*)d_in[0];
  const int* coords = (const int*)d_in[1];
  const float* lin_w = (const float*)d_in[2];
  const float* lin_b = (const float*)d_in[3];
  const float* pfn_g = (const float*)d_in[4];
  const float* pfn_b = (const float*)d_in[5];
  const float* c1_w = (const float*)d_in[6];
  const float* c1_b = (const float*)d_in[7];
  const float* bn1_g = (const float*)d_in[8];
  const float* bn1_b = (const float*)d_in[9];
  const float* c2_w = (const float*)d_in[10];
  const float* c2_b = (const float*)d_in[11];
  const float* bn2_g = (const float*)d_in[12];
  const float* bn2_b = (const float*)d_in[13];
  const float* h1_w = (const float*)d_in[14];
  const float* h1_b = (const float*)d_in[15];
  const float* hbn_g = (const float*)d_in[16];
  const float* hbn_b = (const float*)d_in[17];
  const float* hb_w = (const float*)d_in[18];
  const float* hb_b = (const float*)d_in[19];
  const float* hc_w = (const float*)d_in[20];
  const float* hc_b = (const float*)d_in[21];
  float* out = (float*)d_out;

  // ---- workspace layout (bytes) ----
  char* ws = (char*)d_ws;
  float* pfn_acc = (float*)(ws + 0);         // 512 B
  float* pfn_ss  = (float*)(ws + 512);       // 512 B
  float* bn_acc1 = (float*)(ws + 1024);      // 2048 B
  float* bn_acc2 = (float*)(ws + 3072);      // 2048 B
  float* bn_acc3 = (float*)(ws + 5120);      // 2048 B
  float* coef1   = (float*)(ws + 7168);      // 512 B  (sc/sh, C=64)
  float* coef2   = (float*)(ws + 7680);      // 1024 B (C=128)
  float* coef3   = (float*)(ws + 8704);      // 2048 B (C=256)
  int* winner    = (int*)(ws + 10752);       // 1774224 B
  float* feats   = (float*)(ws + 1785088);   // 5120000 B
  ushort_t* canvas = (ushort_t*)(ws + 6905088);     // 706x674x64  = 60899328 B
  ushort_t* c1p    = (ushort_t*)(ws + 67804416);    // 333x333x64  = 14193792 B (pooled raw)
  ushort_t* c2p    = (ushort_t*)(ws + 81998208);    // 166x166x128 = 7054336 B (pooled raw)
  ushort_t* h1out  = (ushort_t*)(ws + 89052544);    // 166x166x256 = 14108672 B (raw)
  ushort_t* w2c1   = (ushort_t*)(ws + 103161216);   // 73728 B
  ushort_t* w2c2   = (ushort_t*)(ws + 103234944);   // 147456 B
  ushort_t* w2h1   = (ushort_t*)(ws + 103382400);   // 589824 B
  ushort_t* w2hd   = (ushort_t*)(ws + 103972224);   // 147456 B
  float* hpart     = (float*)(ws + 104119680);      // 4x27556x32x4 = 14108672 B

  const int HW3 = 166 * 166;

  // ---- upfront zero-init ----
  hipMemsetAsync(ws, 0, 10752, stream);
  hipMemsetAsync(winner, 0xFF, 1774224, stream);
  hipMemsetAsync(canvas, 0, 60899328, stream);

  // ---- weight prep (Kc=32 layout) ----
  prep_w<<<18, 256, 0, stream>>>(c1_w, w2c1, 64, 64, 2, 2);
  prep_w<<<36, 256, 0, stream>>>(c2_w, w2c2, 64, 128, 4, 2);
  prep_w<<<144, 256, 0, stream>>>(h1_w, w2h1, 128, 256, 8, 4);
  prep_w_head<<<36, 256, 0, stream>>>(hb_w, hc_w, w2hd);

  // ---- PFN ----
  pfn_stats<<<625, 256, 0, stream>>>(pillars, lin_w, lin_b, pfn_acc);
  pfn_finalize<<<1, 64, 0, stream>>>(pfn_acc, pfn_g, pfn_b, pfn_ss);
  pfn_feats<<<5000, 256, 0, stream>>>(pillars, lin_w, lin_b, pfn_ss, feats);

  // ---- scatter ----
  scatter_winner<<<(20000 + 255) / 256, 256, 0, stream>>>(coords, winner, 20000);
  scatter_img<<<5000, 256, 0, stream>>>(coords, winner, feats, canvas, 20000, 706);

  // ---- conv1: 666x666, 64->64, padded canvas in, stats + pool -> c1p raw ----
  conv_mfma<2, 8, false, true, true, false><<<dim3(11, 84, 1), 512, 0, stream>>>(
      canvas, w2c1, c1_b, nullptr, nullptr, c1p, nullptr, bn_acc1, 706, 666, 666, 64, 2,
      2);
  bn_make_coefs<<<1, 64, 0, stream>>>(bn_acc1, bn1_g, bn1_b, 1.f / 443556.f, coef1, 64);

  // ---- conv2: 333x333, 64->128, BN-staged from c1p raw, stats + pool -> c2p ----
  conv_mfma<2, 8, false, true, true, true><<<dim3(6, 42, 2), 512, 0, stream>>>(
      c1p, w2c2, c2_b, nullptr, coef1, c2p, nullptr, bn_acc2, 333, 333, 333, 64, 2, 4);
  bn_make_coefs<<<1, 128, 0, stream>>>(bn_acc2, bn2_g, bn2_b, 1.f / 110889.f, coef2, 128);

  // ---- h1: 166x166, 128->256, BN-staged from c2p raw, oc-split z=8 (stats) ----
  conv_mfma<1, 8, false, true, false, true><<<dim3(3, 21, 8), 512, 0, stream>>>(
      c2p, w2h1, h1_b, nullptr, coef2, h1out, nullptr, bn_acc3, 166, 166, 166, 128, 4,
      8);
  bn_make_coefs<<<1, 256, 0, stream>>>(bn_acc3, hbn_g, hbn_b, 1.f / 27556.f, coef3, 256);

  // ---- heads: BN-staged from h1out raw, K-split z=4, coalesced partials ----
  conv_mfma<1, 4, true, false, false, true><<<dim3(3, 42, 4), 256, 0, stream>>>(
      h1out, w2hd, hb_b, hc_b, coef3, nullptr, hpart, nullptr, 166, 166, 166, 256, 2, 1);
  head_reduce<<<(HW3 + 255) / 256, 256, 0, stream>>>(hpart, out, HW3, 4);
}

// Round 12
// 361.078 us; speedup vs baseline: 1.2978x; 1.0652x over previous
//
#include <hip/hip_runtime.h>
#include <hip/hip_bf16.h>
#include <cstdint>
#include <cstddef>

#define BN_EPS 1e-5f

typedef short short8 __attribute__((ext_vector_type(8)));
typedef float float16 __attribute__((ext_vector_type(16)));
typedef unsigned short ushort_t;

__device__ __forceinline__ float bf2f(ushort_t u) {
  return __uint_as_float(((unsigned int)u) << 16);
}
__device__ __forceinline__ ushort_t f2bf(float f) {
  unsigned int u = __float_as_uint(f);
  u += 0x7FFFu + ((u >> 16) & 1u);
  return (ushort_t)(u >> 16);
}

// ------------------------------------------------------------------
// PFN (fp32)
// ------------------------------------------------------------------

__global__ __launch_bounds__(256) void pfn_stats(
    const float* __restrict__ pillars, const float* __restrict__ lin_w,
    const float* __restrict__ lin_b, float* __restrict__ acc) {
  __shared__ float s_p[288];
  __shared__ float red[512];
  int tid = threadIdx.x;
  int c = tid & 63, rs = tid >> 6;
  float w[9];
#pragma unroll
  for (int d = 0; d < 9; ++d) w[d] = lin_w[c * 9 + d];
  float bl = lin_b[c];
  float s = 0.f, s2 = 0.f;
  long base_row = (long)blockIdx.x * 1024;
  for (int ch = 0; ch < 32; ++ch) {
    long crow = base_row + ch * 32;
    __syncthreads();
    for (int i = tid; i < 288; i += 256) s_p[i] = pillars[crow * 9 + i];
    __syncthreads();
#pragma unroll
    for (int k = 0; k < 8; ++k) {
      const float* pr = &s_p[(rs * 8 + k) * 9];
      float y = bl;
#pragma unroll
      for (int d = 0; d < 9; ++d) y += pr[d] * w[d];
      s += y;
      s2 += y * y;
    }
  }
  red[tid] = s;
  red[tid + 256] = s2;
  __syncthreads();
  if (rs == 0) {
    float ts = red[c] + red[c + 64] + red[c + 128] + red[c + 192];
    float t2 = red[256 + c] + red[256 + c + 64] + red[256 + c + 128] + red[256 + c + 192];
    atomicAdd(&acc[c], ts);
    atomicAdd(&acc[c + 64], t2);
  }
}

__global__ void pfn_finalize(const float* __restrict__ acc, const float* __restrict__ g,
                             const float* __restrict__ b, float* __restrict__ ss) {
  int c = threadIdx.x;  // 64 threads
  const float invN = 1.f / 640000.f;
  float m = acc[c] * invN;
  float v = acc[c + 64] * invN - m * m;
  v = fmaxf(v, 0.f);
  float inv = rsqrtf(v + BN_EPS);
  float sc = g[c] * inv;
  ss[c] = sc;
  ss[c + 64] = b[c] - m * sc;
}

__global__ __launch_bounds__(256) void pfn_feats(
    const float* __restrict__ pillars, const float* __restrict__ lin_w,
    const float* __restrict__ lin_b, const float* __restrict__ ss,
    float* __restrict__ feats) {
  __shared__ float s_p[1152];
  int tid = threadIdx.x;
  int c = tid & 63, pe = tid >> 6;
  long pb = (long)blockIdx.x * 4;
  for (int i = tid; i < 1152; i += 256) s_p[i] = pillars[pb * 288 + i];
  float w[9];
#pragma unroll
  for (int d = 0; d < 9; ++d) w[d] = lin_w[c * 9 + d];
  float bl = lin_b[c];
  float sc = ss[c], sh = ss[c + 64];
  __syncthreads();
  const float* pp = &s_p[pe * 288];
  float m = -1e30f;
#pragma unroll 4
  for (int n = 0; n < 32; ++n) {
    float y = bl;
#pragma unroll
    for (int d = 0; d < 9; ++d) y += pp[n * 9 + d] * w[d];
    float v = fmaxf(y * sc + sh, 0.f);
    m = fmaxf(m, v);
  }
  feats[(pb + pe) * 64 + c] = m;
}

// ------------------------------------------------------------------
// Scatter winner map (numpy last-write-wins)
// ------------------------------------------------------------------

__global__ void scatter_winner(const int* __restrict__ coords, int* __restrict__ winner,
                               int P) {
  int p = blockIdx.x * 256 + threadIdx.x;
  if (p >= P) return;
  int y = coords[p * 3 + 1], x = coords[p * 3 + 2];
  if (y >= 0 && y < 666 && x >= 0 && x < 666) atomicMax(&winner[y * 666 + x], p);
}

// ------------------------------------------------------------------
// Weight prep (merged): OIHW fp32 -> fragment-ordered bf16 (Kc=32 layout)
// ------------------------------------------------------------------

__device__ __forceinline__ void prep_one(const float* __restrict__ w,
                                         ushort_t* __restrict__ w2, int C, int N,
                                         int Ntg, int chunks, int u) {
  int total = chunks * 9 * 2 * Ntg * 64;
  if (u >= total) return;
  int l = u & 63;
  int g = u >> 6;
  int ntg = g % Ntg;
  int g2 = g / Ntg;
  int s = g2 & 1;
  int g3 = g2 >> 1;
  int pos = g3 % 9;
  int cc = g3 / 9;
  int n = ntg * 32 + (l & 31);
  int c0 = cc * 32 + s * 16 + (l >> 5) * 8;
  ushort_t o8[8];
#pragma unroll
  for (int j = 0; j < 8; ++j) {
    int c = c0 + j;
    float v = (n < N && c < C) ? w[((size_t)n * C + c) * 9 + pos] : 0.f;
    o8[j] = f2bf(v);
  }
  *(uint4*)&w2[(size_t)u * 8] = *(const uint4*)o8;
}

__device__ __forceinline__ void prep_head_one(const float* __restrict__ hb,
                                              const float* __restrict__ hc,
                                              ushort_t* __restrict__ w2, int u) {
  int total = 8 * 9 * 2 * 64;
  if (u >= total) return;
  int l = u & 63;
  int g = u >> 6;
  int s = g & 1;
  int g3 = g >> 1;
  int pos = g3 % 9;
  int cc = g3 / 9;
  int n = l & 31;
  int c0 = cc * 32 + s * 16 + (l >> 5) * 8;
  ushort_t o8[8];
#pragma unroll
  for (int j = 0; j < 8; ++j) {
    int c = c0 + j;
    float v = 0.f;
    if (n < 21) v = hb[((size_t)n * 256 + c) * 9 + pos];
    else if (n < 24) v = hc[((size_t)(n - 21) * 256 + c) * 9 + pos];
    o8[j] = f2bf(v);
  }
  *(uint4*)&w2[(size_t)u * 8] = *(const uint4*)o8;
}

// grid 234 x 256
__global__ void prep_all(const float* __restrict__ c1_w, const float* __restrict__ c2_w,
                         const float* __restrict__ h1_w, const float* __restrict__ hb_w,
                         const float* __restrict__ hc_w, ushort_t* __restrict__ w2c1,
                         ushort_t* __restrict__ w2c2, ushort_t* __restrict__ w2h1,
                         ushort_t* __restrict__ w2hd) {
  int b = blockIdx.x;
  int t = threadIdx.x;
  if (b < 18) prep_one(c1_w, w2c1, 64, 64, 2, 2, b * 256 + t);
  else if (b < 54) prep_one(c2_w, w2c2, 64, 128, 4, 2, (b - 18) * 256 + t);
  else if (b < 198) prep_one(h1_w, w2h1, 128, 256, 8, 4, (b - 54) * 256 + t);
  else prep_head_one(hb_w, hc_w, w2hd, (b - 198) * 256 + t);
}

// ------------------------------------------------------------------
// BN coef publish: sc[c], sh[c] from stats accumulators
// ------------------------------------------------------------------

__global__ void bn_make_coefs(const float* __restrict__ acc, const float* __restrict__ g,
                              const float* __restrict__ b, float invN,
                              float* __restrict__ coef, int C) {
  int c = threadIdx.x;
  if (c >= C) return;
  float m = acc[c] * invN;
  float v = fmaxf(acc[c + 256] * invN - m * m, 0.f);
  float sc = g[c] * rsqrtf(v + BN_EPS);
  coef[c] = sc;
  coef[C + c] = b[c] - m * sc;
}

// ------------------------------------------------------------------
// Implicit-GEMM 3x3 conv via v_mfma_f32_32x32x16_bf16.
// Block = WAVES waves. Tile 64 px x WAVES rows, NT*32 oc per block.
// K chunked by 32 ch; stage input (WAVES+2)x66x32 (xor-swizzled) + weights.
// MODE 0: padded raw input (pitch PW).
// MODE 1: BN-stage from raw unpadded HWC: relu(x*sc+sh), bounds->0.
// MODE 2: gather-stage (conv1): winner[cell] -> feats row, fp32->bf16, miss->0.
// HEAD: blockIdx.z = K-split; coalesced fp32 partials into hpart (HWC x32).
// STATS: fused BN stats (full-res, exact).
// POOL: fused raw 2x2 max-pool (valid: BN scale > 0 -> monotone).
// ------------------------------------------------------------------

template <int NT, int WAVES, int MODE, bool HEAD, bool STATS, bool POOL>
__global__ __launch_bounds__(WAVES * 64, WAVES == 8 ? 4 : 3) void conv_mfma(
    const ushort_t* __restrict__ in, const int* __restrict__ winner,
    const float* __restrict__ feats, const ushort_t* __restrict__ w2,
    const float* __restrict__ bias, const float* __restrict__ bias2,
    const float* __restrict__ coef_in, ushort_t* __restrict__ obf,
    float* __restrict__ hpart, float* __restrict__ statacc, int PW, int W, int H, int C,
    int nchunks, int Ntg) {
  constexpr int NTHREADS = WAVES * 64;
  __shared__ ushort_t s_in[(WAVES + 2) * 66 * 32];
  __shared__ ushort_t s_w[9 * 2 * NT * 512];
  const int tid = threadIdx.x;
  const int lane = tid & 63, wv = tid >> 6;
  const int lc = lane & 31, lh = lane >> 5;
  const int x0 = blockIdx.x * 64, y0 = blockIdx.y * WAVES;
  const int z = blockIdx.z;
  const int cc0 = HEAD ? z * nchunks : 0;
  const int z_oc = HEAD ? 0 : z;

  // per-lane A-address precompute
  int pc[2][2][3];
#pragma unroll
  for (int s = 0; s < 2; ++s)
#pragma unroll
    for (int Mt = 0; Mt < 2; ++Mt)
#pragma unroll
      for (int kx = 0; kx < 3; ++kx) {
        int col = Mt * 32 + kx + lc;
        int q = (2 * s + lh) ^ ((col >> 1) & 3);
        pc[s][Mt][kx] = col * 32 + q * 8;
      }

  float bv[NT];
#pragma unroll
  for (int nt = 0; nt < NT; ++nt) {
    if (HEAD) {
      bv[nt] = (z == 0) ? (lc < 21 ? bias[lc] : (lc < 24 ? bias2[lc - 21] : 0.f)) : 0.f;
    } else {
      bv[nt] = bias[(z * NT + nt) * 32 + lc];
    }
  }
  float16 acc[2][NT];
#pragma unroll
  for (int Mt = 0; Mt < 2; ++Mt)
#pragma unroll
    for (int nt = 0; nt < NT; ++nt)
#pragma unroll
      for (int r = 0; r < 16; ++r) acc[Mt][nt][r] = bv[nt];

  const ushort_t* inbase = (MODE == 0) ? in + ((size_t)y0 * PW + x0) * C : in;
  const int sg = tid & 3;  // MODE 1/2: fixed channel group per thread
  const int tpos = tid >> 2;
  constexpr int TPOS = NTHREADS / 4;

  for (int cc = 0; cc < nchunks; ++cc) {
    const int ccg = cc0 + cc;
    __syncthreads();
    if (MODE == 2) {
      for (int p = tpos; p < (WAVES + 2) * 66; p += TPOS) {
        int r = p / 66, col = p - r * 66;
        int gy = y0 - 1 + r, gx = x0 - 1 + col;
        ushort_t v8[8] = {0, 0, 0, 0, 0, 0, 0, 0};
        if (gy >= 0 && gy < H && gx >= 0 && gx < W) {
          int pw = winner[gy * 666 + gx];
          if (pw >= 0) {
            const float* fp = feats + (size_t)pw * 64 + ccg * 32 + sg * 8;
            float4 f0 = *(const float4*)fp;
            float4 f1 = *(const float4*)(fp + 4);
            v8[0] = f2bf(f0.x); v8[1] = f2bf(f0.y);
            v8[2] = f2bf(f0.z); v8[3] = f2bf(f0.w);
            v8[4] = f2bf(f1.x); v8[5] = f2bf(f1.y);
            v8[6] = f2bf(f1.z); v8[7] = f2bf(f1.w);
          }
        }
        int f = sg ^ ((col >> 1) & 3);
        *(uint4*)&s_in[(r * 66 + col) * 32 + f * 8] = *(const uint4*)v8;
      }
    } else if (MODE == 1) {
      float sc8[8], sh8[8];
      {
        int ch = ccg * 32 + sg * 8;
        float4 a0 = *(const float4*)&coef_in[ch];
        float4 a1 = *(const float4*)&coef_in[ch + 4];
        float4 b0 = *(const float4*)&coef_in[C + ch];
        float4 b1 = *(const float4*)&coef_in[C + ch + 4];
        sc8[0] = a0.x; sc8[1] = a0.y; sc8[2] = a0.z; sc8[3] = a0.w;
        sc8[4] = a1.x; sc8[5] = a1.y; sc8[6] = a1.z; sc8[7] = a1.w;
        sh8[0] = b0.x; sh8[1] = b0.y; sh8[2] = b0.z; sh8[3] = b0.w;
        sh8[4] = b1.x; sh8[5] = b1.y; sh8[6] = b1.z; sh8[7] = b1.w;
      }
      for (int p = tpos; p < (WAVES + 2) * 66; p += TPOS) {
        int r = p / 66, col = p - r * 66;
        int gy = y0 - 1 + r, gx = x0 - 1 + col;
        ushort_t v8[8] = {0, 0, 0, 0, 0, 0, 0, 0};
        if (gy >= 0 && gy < H && gx >= 0 && gx < W) {
          const ushort_t* src = in + ((size_t)gy * W + gx) * C + ccg * 32 + sg * 8;
          uint4 raw = *(const uint4*)src;
          const ushort_t* rp = (const ushort_t*)&raw;
#pragma unroll
          for (int j = 0; j < 8; ++j)
            v8[j] = f2bf(fmaxf(bf2f(rp[j]) * sc8[j] + sh8[j], 0.f));
        }
        int f = sg ^ ((col >> 1) & 3);
        *(uint4*)&s_in[(r * 66 + col) * 32 + f * 8] = *(const uint4*)v8;
      }
    } else {
      for (int u = tid; u < (WAVES + 2) * 264; u += NTHREADS) {
        int r = u / 264;
        int sr = u - r * 264;
        int col = sr >> 2, f = sr & 3;
        int g = f ^ ((col >> 1) & 3);
        const ushort_t* src = inbase + ((size_t)r * PW + col) * C + ccg * 32 + g * 8;
        *(uint4*)&s_in[(r * 66 + col) * 32 + f * 8] = *(const uint4*)src;
      }
    }
    // stage weight slice: [pos*2+s][nt] x 64 lanes x 16 B
    const int NW = NT * 1152;
    for (int u = tid; u < NW; u += NTHREADS) {
      int l16 = u & 63, grp = u >> 6;
      int nt = grp % NT, ps = grp / NT;
      const ushort_t* src =
          w2 + ((size_t)((ccg * 18 + ps) * Ntg + z_oc * NT + nt) * 64 + l16) * 8;
      *(uint4*)&s_w[(size_t)u * 8] = *(const uint4*)src;
    }
    __syncthreads();
#pragma unroll
    for (int ky = 0; ky < 3; ++ky) {
      int rowoff = (wv + ky) * (66 * 32);
#pragma unroll
      for (int kx = 0; kx < 3; ++kx) {
        const int pos = ky * 3 + kx;
#pragma unroll
        for (int s = 0; s < 2; ++s) {
          short8 Bf[NT];
#pragma unroll
          for (int nt = 0; nt < NT; ++nt)
            Bf[nt] = *(const short8*)&s_w[((pos * 2 + s) * NT + nt) * 512 + lane * 8];
#pragma unroll
          for (int Mt = 0; Mt < 2; ++Mt) {
            short8 Af = *(const short8*)&s_in[rowoff + pc[s][Mt][kx]];
#pragma unroll
            for (int nt = 0; nt < NT; ++nt)
              acc[Mt][nt] =
                  __builtin_amdgcn_mfma_f32_32x32x16_bf16(Af, Bf[nt], acc[Mt][nt], 0, 0, 0);
          }
        }
      }
    }
  }

  // ---- epilogue ----
  const int y = y0 + wv;
  const bool yok = (y < H);
  const int Ntot = Ntg * 32;

  if (HEAD) {
    if (yok) {
      float* hp = hpart + (size_t)z * (size_t)(H * W) * 32;
#pragma unroll
      for (int Mt = 0; Mt < 2; ++Mt)
#pragma unroll
        for (int r = 0; r < 16; ++r) {
          int m = (r & 3) + 8 * (r >> 2) + 4 * lh;
          int x = x0 + Mt * 32 + m;
          if (x < W) {
            size_t sp = (size_t)y * W + x;
            hp[sp * 32 + lc] = acc[Mt][0][r];  // coalesced
          }
        }
    }
    return;
  }

  if (!POOL) {
    if (yok) {
#pragma unroll
      for (int Mt = 0; Mt < 2; ++Mt)
#pragma unroll
        for (int r = 0; r < 16; ++r) {
          int m = (r & 3) + 8 * (r >> 2) + 4 * lh;
          int x = x0 + Mt * 32 + m;
          if (x < W) {
            size_t sp = (size_t)y * W + x;
#pragma unroll
            for (int nt = 0; nt < NT; ++nt) {
              int oc = (z * NT + nt) * 32 + lc;
              obf[sp * Ntot + oc] = f2bf(acc[Mt][nt][r]);
            }
          }
        }
    }
  }

  if (STATS) {
    float s1[NT], s2[NT];
#pragma unroll
    for (int nt = 0; nt < NT; ++nt) { s1[nt] = 0.f; s2[nt] = 0.f; }
    if (yok) {
#pragma unroll
      for (int Mt = 0; Mt < 2; ++Mt)
#pragma unroll
        for (int r = 0; r < 16; ++r) {
          int m = (r & 3) + 8 * (r >> 2) + 4 * lh;
          int x = x0 + Mt * 32 + m;
          if (x < W) {
#pragma unroll
            for (int nt = 0; nt < NT; ++nt) {
              float v = acc[Mt][nt][r];
              s1[nt] += v;
              s2[nt] += v * v;
            }
          }
        }
    }
#pragma unroll
    for (int nt = 0; nt < NT; ++nt) {
      s1[nt] += __shfl_xor(s1[nt], 32);
      s2[nt] += __shfl_xor(s2[nt], 32);
    }
    __syncthreads();  // all MFMA LDS reads done; reuse s_in as fp32 scratch
    float* red = (float*)s_in;
    if (lh == 0) {
#pragma unroll
      for (int nt = 0; nt < NT; ++nt) {
        red[(wv * NT + nt) * 32 + lc] = s1[nt];
        red[WAVES * NT * 32 + (wv * NT + nt) * 32 + lc] = s2[nt];
      }
    }
    __syncthreads();
    if (wv == 0 && lh == 0) {
#pragma unroll
      for (int nt = 0; nt < NT; ++nt) {
        float a = 0.f, b = 0.f;
#pragma unroll
        for (int w8 = 0; w8 < WAVES; ++w8) {
          a += red[(w8 * NT + nt) * 32 + lc];
          b += red[WAVES * NT * 32 + (w8 * NT + nt) * 32 + lc];
        }
        int ch = (z * NT + nt) * 32 + lc;
        atomicAdd(&statacc[ch], a);
        atomicAdd(&statacc[ch + 256], b);
      }
    }
  }

  if (POOL) {
    const int OWp = W >> 1, OHp = H >> 1;
    float hm[2][NT][8];
#pragma unroll
    for (int Mt = 0; Mt < 2; ++Mt)
#pragma unroll
      for (int nt = 0; nt < NT; ++nt)
#pragma unroll
        for (int i = 0; i < 8; ++i)
          hm[Mt][nt][i] = fmaxf(acc[Mt][nt][2 * i], acc[Mt][nt][2 * i + 1]);
    __syncthreads();
    float* pl = (float*)s_in;
    if (wv & 1) {
#pragma unroll
      for (int Mt = 0; Mt < 2; ++Mt)
#pragma unroll
        for (int nt = 0; nt < NT; ++nt)
#pragma unroll
          for (int i = 0; i < 8; ++i)
            pl[((((wv >> 1) * 2 + Mt) * NT + nt) * 8 + i) * 64 + lane] = hm[Mt][nt][i];
    }
    __syncthreads();
    if (!(wv & 1)) {
      int oy = (y0 + wv) >> 1;
      if (oy < OHp) {
#pragma unroll
        for (int Mt = 0; Mt < 2; ++Mt)
#pragma unroll
          for (int i = 0; i < 8; ++i) {
            int pxl = Mt * 16 + (i >> 1) * 4 + (i & 1) + 2 * lh;
            int ox = (x0 >> 1) + pxl;
            if (ox < OWp) {
#pragma unroll
              for (int nt = 0; nt < NT; ++nt) {
                float v = fmaxf(
                    hm[Mt][nt][i],
                    pl[((((wv >> 1) * 2 + Mt) * NT + nt) * 8 + i) * 64 + lane]);
                int oc = (z * NT + nt) * 32 + lc;
                obf[((size_t)oy * OWp + ox) * Ntot + oc] = f2bf(v);
              }
            }
          }
      }
    }
  }
}

// ------------------------------------------------------------------
// Head reduce: sum nz HWC(x32) fp32 partial slices, transpose through
// padded LDS, write 24 contiguous CHW channel planes into d_out.
// ------------------------------------------------------------------

__global__ __launch_bounds__(256) void head_reduce(const float* __restrict__ hp,
                                                   float* __restrict__ out, int HW,
                                                   int nz) {
  __shared__ float t[256 * 33];
  int tid = threadIdx.x;
  int sp0 = blockIdx.x * 256;
  int lim = (HW - sp0) * 32;
#pragma unroll 4
  for (int i = 0; i < 32; ++i) {
    int e = i * 256 + tid;
    float s = 0.f;
    if (e < lim) {
      size_t gidx = (size_t)sp0 * 32 + e;
      for (int z = 0; z < nz; ++z) s += hp[(size_t)z * HW * 32 + gidx];
    }
    t[(e >> 5) * 33 + (e & 31)] = s;
  }
  __syncthreads();
  int sp = sp0 + tid;
  if (sp < HW) {
#pragma unroll
    for (int ch = 0; ch < 24; ++ch)
      out[(size_t)ch * HW + sp] = t[tid * 33 + ch];
  }
}

// ------------------------------------------------------------------

extern "C" void kernel_launch(void* const* d_in, const int* in_sizes, int n_in,
                              void* d_out, int out_size, void* d_ws, size_t ws_size,
                              hipStream_t stream) {
  (void)in_sizes; (void)n_in; (void)out_size; (void)ws_size;
  const float* pillars = (const float*)d_in[0];
  const int* coords = (const int*)d_in[1];
  const float* lin_w = (const float*)d_in[2];
  const float* lin_b = (const float*)d_in[3];
  const float* pfn_g = (const float*)d_in[4];
  const float* pfn_b = (const float*)d_in[5];
  const float* c1_w = (const float*)d_in[6];
  const float* c1_b = (const float*)d_in[7];
  const float* bn1_g = (const float*)d_in[8];
  const float* bn1_b = (const float*)d_in[9];
  const float* c2_w = (const float*)d_in[10];
  const float* c2_b = (const float*)d_in[11];
  const float* bn2_g = (const float*)d_in[12];
  const float* bn2_b = (const float*)d_in[13];
  const float* h1_w = (const float*)d_in[14];
  const float* h1_b = (const float*)d_in[15];
  const float* hbn_g = (const float*)d_in[16];
  const float* hbn_b = (const float*)d_in[17];
  const float* hb_w = (const float*)d_in[18];
  const float* hb_b = (const float*)d_in[19];
  const float* hc_w = (const float*)d_in[20];
  const float* hc_b = (const float*)d_in[21];
  float* out = (float*)d_out;

  // ---- workspace layout (bytes) ----
  char* ws = (char*)d_ws;
  float* pfn_acc = (float*)(ws + 0);         // 512 B
  float* pfn_ss  = (float*)(ws + 512);       // 512 B
  float* bn_acc1 = (float*)(ws + 1024);      // 2048 B
  float* bn_acc2 = (float*)(ws + 3072);      // 2048 B
  float* bn_acc3 = (float*)(ws + 5120);      // 2048 B
  float* coef1   = (float*)(ws + 7168);      // 512 B
  float* coef2   = (float*)(ws + 7680);      // 1024 B
  float* coef3   = (float*)(ws + 8704);      // 2048 B
  int* winner    = (int*)(ws + 10752);       // 1774224 B
  float* feats   = (float*)(ws + 1785088);   // 5120000 B
  ushort_t* c1p    = (ushort_t*)(ws + 6905088);    // 333x333x64  = 14193792 B (pooled raw)
  ushort_t* c2p    = (ushort_t*)(ws + 21098880);   // 166x166x128 = 7054336 B (pooled raw)
  ushort_t* h1out  = (ushort_t*)(ws + 28153216);   // 166x166x256 = 14108672 B (raw)
  ushort_t* w2c1   = (ushort_t*)(ws + 42261888);   // 73728 B
  ushort_t* w2c2   = (ushort_t*)(ws + 42335616);   // 147456 B
  ushort_t* w2h1   = (ushort_t*)(ws + 42483072);   // 589824 B
  ushort_t* w2hd   = (ushort_t*)(ws + 43072896);   // 147456 B
  float* hpart     = (float*)(ws + 43220352);      // 4x27556x32x4 = 14108672 B

  const int HW3 = 166 * 166;

  // ---- upfront zero-init (no canvas anymore) ----
  hipMemsetAsync(ws, 0, 10752, stream);
  hipMemsetAsync(winner, 0xFF, 1774224, stream);

  // ---- weight prep (merged) ----
  prep_all<<<234, 256, 0, stream>>>(c1_w, c2_w, h1_w, hb_w, hc_w, w2c1, w2c2, w2h1,
                                    w2hd);

  // ---- PFN ----
  pfn_stats<<<625, 256, 0, stream>>>(pillars, lin_w, lin_b, pfn_acc);
  pfn_finalize<<<1, 64, 0, stream>>>(pfn_acc, pfn_g, pfn_b, pfn_ss);
  pfn_feats<<<5000, 256, 0, stream>>>(pillars, lin_w, lin_b, pfn_ss, feats);

  // ---- scatter winner map ----
  scatter_winner<<<(20000 + 255) / 256, 256, 0, stream>>>(coords, winner, 20000);

  // ---- conv1: gather-staged from winner/feats, stats + pool -> c1p raw ----
  conv_mfma<2, 8, 2, false, true, true><<<dim3(11, 84, 1), 512, 0, stream>>>(
      nullptr, winner, feats, w2c1, c1_b, nullptr, nullptr, c1p, nullptr, bn_acc1, 666,
      666, 666, 64, 2, 2);
  bn_make_coefs<<<1, 64, 0, stream>>>(bn_acc1, bn1_g, bn1_b, 1.f / 443556.f, coef1, 64);

  // ---- conv2: BN-staged from c1p raw, stats + pool -> c2p raw ----
  conv_mfma<2, 8, 1, false, true, true><<<dim3(6, 42, 2), 512, 0, stream>>>(
      c1p, nullptr, nullptr, w2c2, c2_b, nullptr, coef1, c2p, nullptr, bn_acc2, 333, 333,
      333, 64, 2, 4);
  bn_make_coefs<<<1, 128, 0, stream>>>(bn_acc2, bn2_g, bn2_b, 1.f / 110889.f, coef2, 128);

  // ---- h1: BN-staged from c2p raw, NT=2 WAVES=4 oc-split z=4 (stats) ----
  conv_mfma<2, 4, 1, false, true, false><<<dim3(3, 42, 4), 256, 0, stream>>>(
      c2p, nullptr, nullptr, w2h1, h1_b, nullptr, coef2, h1out, nullptr, bn_acc3, 166,
      166, 166, 128, 4, 8);
  bn_make_coefs<<<1, 256, 0, stream>>>(bn_acc3, hbn_g, hbn_b, 1.f / 27556.f, coef3, 256);

  // ---- heads: BN-staged from h1out raw, K-split z=4, coalesced partials ----
  conv_mfma<1, 4, 1, true, false, false><<<dim3(3, 42, 4), 256, 0, stream>>>(
      h1out, nullptr, nullptr, w2hd, hb_b, hc_b, coef3, nullptr, hpart, nullptr, 166,
      166, 166, 256, 2, 1);
  head_reduce<<<(HW3 + 255) / 256, 256, 0, stream>>>(hpart, out, HW3, 4);
}

// Round 13
// 354.851 us; speedup vs baseline: 1.3206x; 1.0175x over previous
//
#include <hip/hip_runtime.h>
#include <hip/hip_bf16.h>
#include <cstdint>
#include <cstddef>

#define BN_EPS 1e-5f

typedef short short8 __attribute__((ext_vector_type(8)));
typedef float float16 __attribute__((ext_vector_type(16)));
typedef unsigned short ushort_t;

__device__ __forceinline__ float bf2f(ushort_t u) {
  return __uint_as_float(((unsigned int)u) << 16);
}
__device__ __forceinline__ ushort_t f2bf(float f) {
  unsigned int u = __float_as_uint(f);
  u += 0x7FFFu + ((u >> 16) & 1u);
  return (ushort_t)(u >> 16);
}

// ------------------------------------------------------------------
// PFN (fp32 compute, bf16 feats output)
// ------------------------------------------------------------------

__global__ __launch_bounds__(256) void pfn_stats(
    const float* __restrict__ pillars, const float* __restrict__ lin_w,
    const float* __restrict__ lin_b, float* __restrict__ acc) {
  __shared__ float s_p[288];
  __shared__ float red[512];
  int tid = threadIdx.x;
  int c = tid & 63, rs = tid >> 6;
  float w[9];
#pragma unroll
  for (int d = 0; d < 9; ++d) w[d] = lin_w[c * 9 + d];
  float bl = lin_b[c];
  float s = 0.f, s2 = 0.f;
  long base_row = (long)blockIdx.x * 1024;
  for (int ch = 0; ch < 32; ++ch) {
    long crow = base_row + ch * 32;
    __syncthreads();
    for (int i = tid; i < 288; i += 256) s_p[i] = pillars[crow * 9 + i];
    __syncthreads();
#pragma unroll
    for (int k = 0; k < 8; ++k) {
      const float* pr = &s_p[(rs * 8 + k) * 9];
      float y = bl;
#pragma unroll
      for (int d = 0; d < 9; ++d) y += pr[d] * w[d];
      s += y;
      s2 += y * y;
    }
  }
  red[tid] = s;
  red[tid + 256] = s2;
  __syncthreads();
  if (rs == 0) {
    float ts = red[c] + red[c + 64] + red[c + 128] + red[c + 192];
    float t2 = red[256 + c] + red[256 + c + 64] + red[256 + c + 128] + red[256 + c + 192];
    atomicAdd(&acc[c], ts);
    atomicAdd(&acc[c + 64], t2);
  }
}

__global__ void pfn_finalize(const float* __restrict__ acc, const float* __restrict__ g,
                             const float* __restrict__ b, float* __restrict__ ss) {
  int c = threadIdx.x;  // 64 threads
  const float invN = 1.f / 640000.f;
  float m = acc[c] * invN;
  float v = acc[c + 64] * invN - m * m;
  v = fmaxf(v, 0.f);
  float inv = rsqrtf(v + BN_EPS);
  float sc = g[c] * inv;
  ss[c] = sc;
  ss[c + 64] = b[c] - m * sc;
}

__global__ __launch_bounds__(256) void pfn_feats(
    const float* __restrict__ pillars, const float* __restrict__ lin_w,
    const float* __restrict__ lin_b, const float* __restrict__ ss,
    ushort_t* __restrict__ feats) {
  __shared__ float s_p[1152];
  int tid = threadIdx.x;
  int c = tid & 63, pe = tid >> 6;
  long pb = (long)blockIdx.x * 4;
  for (int i = tid; i < 1152; i += 256) s_p[i] = pillars[pb * 288 + i];
  float w[9];
#pragma unroll
  for (int d = 0; d < 9; ++d) w[d] = lin_w[c * 9 + d];
  float bl = lin_b[c];
  float sc = ss[c], sh = ss[c + 64];
  __syncthreads();
  const float* pp = &s_p[pe * 288];
  float m = -1e30f;
#pragma unroll 4
  for (int n = 0; n < 32; ++n) {
    float y = bl;
#pragma unroll
    for (int d = 0; d < 9; ++d) y += pp[n * 9 + d] * w[d];
    float v = fmaxf(y * sc + sh, 0.f);
    m = fmaxf(m, v);
  }
  feats[(pb + pe) * 64 + c] = f2bf(m);
}

// ------------------------------------------------------------------
// Scatter winner map (numpy last-write-wins)
// ------------------------------------------------------------------

__global__ void scatter_winner(const int* __restrict__ coords, int* __restrict__ winner,
                               int P) {
  int p = blockIdx.x * 256 + threadIdx.x;
  if (p >= P) return;
  int y = coords[p * 3 + 1], x = coords[p * 3 + 2];
  if (y >= 0 && y < 666 && x >= 0 && x < 666) atomicMax(&winner[y * 666 + x], p);
}

// ------------------------------------------------------------------
// Weight prep (merged): OIHW fp32 -> fragment-ordered bf16 (Kc=32 layout)
// ------------------------------------------------------------------

__device__ __forceinline__ void prep_one(const float* __restrict__ w,
                                         ushort_t* __restrict__ w2, int C, int N,
                                         int Ntg, int chunks, int u) {
  int total = chunks * 9 * 2 * Ntg * 64;
  if (u >= total) return;
  int l = u & 63;
  int g = u >> 6;
  int ntg = g % Ntg;
  int g2 = g / Ntg;
  int s = g2 & 1;
  int g3 = g2 >> 1;
  int pos = g3 % 9;
  int cc = g3 / 9;
  int n = ntg * 32 + (l & 31);
  int c0 = cc * 32 + s * 16 + (l >> 5) * 8;
  ushort_t o8[8];
#pragma unroll
  for (int j = 0; j < 8; ++j) {
    int c = c0 + j;
    float v = (n < N && c < C) ? w[((size_t)n * C + c) * 9 + pos] : 0.f;
    o8[j] = f2bf(v);
  }
  *(uint4*)&w2[(size_t)u * 8] = *(const uint4*)o8;
}

__device__ __forceinline__ void prep_head_one(const float* __restrict__ hb,
                                              const float* __restrict__ hc,
                                              ushort_t* __restrict__ w2, int u) {
  int total = 8 * 9 * 2 * 64;
  if (u >= total) return;
  int l = u & 63;
  int g = u >> 6;
  int s = g & 1;
  int g3 = g >> 1;
  int pos = g3 % 9;
  int cc = g3 / 9;
  int n = l & 31;
  int c0 = cc * 32 + s * 16 + (l >> 5) * 8;
  ushort_t o8[8];
#pragma unroll
  for (int j = 0; j < 8; ++j) {
    int c = c0 + j;
    float v = 0.f;
    if (n < 21) v = hb[((size_t)n * 256 + c) * 9 + pos];
    else if (n < 24) v = hc[((size_t)(n - 21) * 256 + c) * 9 + pos];
    o8[j] = f2bf(v);
  }
  *(uint4*)&w2[(size_t)u * 8] = *(const uint4*)o8;
}

// grid 234 x 256
__global__ void prep_all(const float* __restrict__ c1_w, const float* __restrict__ c2_w,
                         const float* __restrict__ h1_w, const float* __restrict__ hb_w,
                         const float* __restrict__ hc_w, ushort_t* __restrict__ w2c1,
                         ushort_t* __restrict__ w2c2, ushort_t* __restrict__ w2h1,
                         ushort_t* __restrict__ w2hd) {
  int b = blockIdx.x;
  int t = threadIdx.x;
  if (b < 18) prep_one(c1_w, w2c1, 64, 64, 2, 2, b * 256 + t);
  else if (b < 54) prep_one(c2_w, w2c2, 64, 128, 4, 2, (b - 18) * 256 + t);
  else if (b < 198) prep_one(h1_w, w2h1, 128, 256, 8, 4, (b - 54) * 256 + t);
  else prep_head_one(hb_w, hc_w, w2hd, (b - 198) * 256 + t);
}

// ------------------------------------------------------------------
// BN coef publish
// ------------------------------------------------------------------

__global__ void bn_make_coefs(const float* __restrict__ acc, const float* __restrict__ g,
                              const float* __restrict__ b, float invN,
                              float* __restrict__ coef, int C) {
  int c = threadIdx.x;
  if (c >= C) return;
  float m = acc[c] * invN;
  float v = fmaxf(acc[c + 256] * invN - m * m, 0.f);
  float sc = g[c] * rsqrtf(v + BN_EPS);
  coef[c] = sc;
  coef[C + c] = b[c] - m * sc;
}

// ------------------------------------------------------------------
// Implicit-GEMM 3x3 conv via v_mfma_f32_32x32x16_bf16.
// MODE 1: BN-stage from raw unpadded HWC: relu(x*sc+sh), bounds->0.
// MODE 2: gather-stage (conv1): winner[cell] -> bf16 feats row, miss->0.
// Per-position addressing/bounds/winner hoisted OUT of the K-chunk loop.
// HEAD: z = K-split; coalesced fp32 partials. STATS: fused BN stats.
// POOL: fused raw 2x2 max-pool (BN scale > 0 -> monotone).
// ------------------------------------------------------------------

template <int NT, int WAVES, int MODE, bool HEAD, bool STATS, bool POOL>
__global__ __launch_bounds__(WAVES * 64, WAVES == 8 ? 4 : 3) void conv_mfma(
    const ushort_t* __restrict__ in, const int* __restrict__ winner,
    const ushort_t* __restrict__ feats, const ushort_t* __restrict__ w2,
    const float* __restrict__ bias, const float* __restrict__ bias2,
    const float* __restrict__ coef_in, ushort_t* __restrict__ obf,
    float* __restrict__ hpart, float* __restrict__ statacc, int W, int H, int C,
    int nchunks, int Ntg) {
  constexpr int NTHREADS = WAVES * 64;
  __shared__ ushort_t s_in[(WAVES + 2) * 66 * 32];
  __shared__ ushort_t s_w[9 * 2 * NT * 512];
  const int tid = threadIdx.x;
  const int lane = tid & 63, wv = tid >> 6;
  const int lc = lane & 31, lh = lane >> 5;
  const int x0 = blockIdx.x * 64, y0 = blockIdx.y * WAVES;
  const int z = blockIdx.z;
  const int cc0 = HEAD ? z * nchunks : 0;
  const int z_oc = HEAD ? 0 : z;

  // per-lane A-address precompute
  int pc[2][2][3];
#pragma unroll
  for (int s = 0; s < 2; ++s)
#pragma unroll
    for (int Mt = 0; Mt < 2; ++Mt)
#pragma unroll
      for (int kx = 0; kx < 3; ++kx) {
        int col = Mt * 32 + kx + lc;
        int q = (2 * s + lh) ^ ((col >> 1) & 3);
        pc[s][Mt][kx] = col * 32 + q * 8;
      }

  // ---- hoisted staging descriptors ----
  const int sg = tid & 3;
  const int tpos = tid >> 2;
  constexpr int TPOS = NTHREADS / 4;
  constexpr int NPOS = (WAVES + 2) * 66;
  constexpr int NIT = (NPOS + TPOS - 1) / TPOS;
  int ldst[NIT], gsrc[NIT];
#pragma unroll
  for (int it = 0; it < NIT; ++it) {
    ldst[it] = -1;
    gsrc[it] = -1;
    int p = tpos + it * TPOS;
    if (p < NPOS) {
      int r = p / 66, col = p - r * 66;
      int f = sg ^ ((col >> 1) & 3);
      ldst[it] = (r * 66 + col) * 32 + f * 8;
      int gy = y0 - 1 + r, gx = x0 - 1 + col;
      if (gy >= 0 && gy < H && gx >= 0 && gx < W) {
        if (MODE == 2) {
          int pw = winner[gy * 666 + gx];
          if (pw >= 0) gsrc[it] = pw * 64 + sg * 8;
        } else {
          gsrc[it] = (gy * W + gx) * C + sg * 8;
        }
      }
    }
  }

  float bv[NT];
#pragma unroll
  for (int nt = 0; nt < NT; ++nt) {
    if (HEAD) {
      bv[nt] = (z == 0) ? (lc < 21 ? bias[lc] : (lc < 24 ? bias2[lc - 21] : 0.f)) : 0.f;
    } else {
      bv[nt] = bias[(z * NT + nt) * 32 + lc];
    }
  }
  float16 acc[2][NT];
#pragma unroll
  for (int Mt = 0; Mt < 2; ++Mt)
#pragma unroll
    for (int nt = 0; nt < NT; ++nt)
#pragma unroll
      for (int r = 0; r < 16; ++r) acc[Mt][nt][r] = bv[nt];

  for (int cc = 0; cc < nchunks; ++cc) {
    const int ccg = cc0 + cc;
    __syncthreads();
    if (MODE == 2) {
#pragma unroll
      for (int it = 0; it < NIT; ++it) {
        if (ldst[it] < 0) continue;
        uint4 v = make_uint4(0, 0, 0, 0);
        if (gsrc[it] >= 0) v = *(const uint4*)&feats[gsrc[it] + ccg * 32];
        *(uint4*)&s_in[ldst[it]] = v;
      }
    } else {  // MODE 1
      float sc8[8], sh8[8];
      {
        int ch = ccg * 32 + sg * 8;
        float4 a0 = *(const float4*)&coef_in[ch];
        float4 a1 = *(const float4*)&coef_in[ch + 4];
        float4 b0 = *(const float4*)&coef_in[C + ch];
        float4 b1 = *(const float4*)&coef_in[C + ch + 4];
        sc8[0] = a0.x; sc8[1] = a0.y; sc8[2] = a0.z; sc8[3] = a0.w;
        sc8[4] = a1.x; sc8[5] = a1.y; sc8[6] = a1.z; sc8[7] = a1.w;
        sh8[0] = b0.x; sh8[1] = b0.y; sh8[2] = b0.z; sh8[3] = b0.w;
        sh8[4] = b1.x; sh8[5] = b1.y; sh8[6] = b1.z; sh8[7] = b1.w;
      }
#pragma unroll
      for (int it = 0; it < NIT; ++it) {
        if (ldst[it] < 0) continue;
        ushort_t v8[8] = {0, 0, 0, 0, 0, 0, 0, 0};
        if (gsrc[it] >= 0) {
          uint4 raw = *(const uint4*)&in[gsrc[it] + ccg * 32];
          const ushort_t* rp = (const ushort_t*)&raw;
#pragma unroll
          for (int j = 0; j < 8; ++j)
            v8[j] = f2bf(fmaxf(bf2f(rp[j]) * sc8[j] + sh8[j], 0.f));
        }
        *(uint4*)&s_in[ldst[it]] = *(const uint4*)v8;
      }
    }
    // stage weight slice
    const int NW = NT * 1152;
    for (int u = tid; u < NW; u += NTHREADS) {
      int l16 = u & 63, grp = u >> 6;
      int nt = grp % NT, ps = grp / NT;
      const ushort_t* src =
          w2 + ((size_t)((ccg * 18 + ps) * Ntg + z_oc * NT + nt) * 64 + l16) * 8;
      *(uint4*)&s_w[(size_t)u * 8] = *(const uint4*)src;
    }
    __syncthreads();
#pragma unroll
    for (int ky = 0; ky < 3; ++ky) {
      int rowoff = (wv + ky) * (66 * 32);
#pragma unroll
      for (int kx = 0; kx < 3; ++kx) {
        const int pos = ky * 3 + kx;
#pragma unroll
        for (int s = 0; s < 2; ++s) {
          short8 Bf[NT];
#pragma unroll
          for (int nt = 0; nt < NT; ++nt)
            Bf[nt] = *(const short8*)&s_w[((pos * 2 + s) * NT + nt) * 512 + lane * 8];
#pragma unroll
          for (int Mt = 0; Mt < 2; ++Mt) {
            short8 Af = *(const short8*)&s_in[rowoff + pc[s][Mt][kx]];
#pragma unroll
            for (int nt = 0; nt < NT; ++nt)
              acc[Mt][nt] =
                  __builtin_amdgcn_mfma_f32_32x32x16_bf16(Af, Bf[nt], acc[Mt][nt], 0, 0, 0);
          }
        }
      }
    }
  }

  // ---- epilogue ----
  const int y = y0 + wv;
  const bool yok = (y < H);
  const int Ntot = Ntg * 32;

  if (HEAD) {
    if (yok) {
      float* hp = hpart + (size_t)z * (size_t)(H * W) * 32;
#pragma unroll
      for (int Mt = 0; Mt < 2; ++Mt)
#pragma unroll
        for (int r = 0; r < 16; ++r) {
          int m = (r & 3) + 8 * (r >> 2) + 4 * lh;
          int x = x0 + Mt * 32 + m;
          if (x < W) {
            size_t sp = (size_t)y * W + x;
            hp[sp * 32 + lc] = acc[Mt][0][r];  // coalesced
          }
        }
    }
    return;
  }

  if (!POOL) {
    if (yok) {
#pragma unroll
      for (int Mt = 0; Mt < 2; ++Mt)
#pragma unroll
        for (int r = 0; r < 16; ++r) {
          int m = (r & 3) + 8 * (r >> 2) + 4 * lh;
          int x = x0 + Mt * 32 + m;
          if (x < W) {
            size_t sp = (size_t)y * W + x;
#pragma unroll
            for (int nt = 0; nt < NT; ++nt) {
              int oc = (z * NT + nt) * 32 + lc;
              obf[sp * Ntot + oc] = f2bf(acc[Mt][nt][r]);
            }
          }
        }
    }
  }

  if (STATS) {
    float s1[NT], s2[NT];
#pragma unroll
    for (int nt = 0; nt < NT; ++nt) { s1[nt] = 0.f; s2[nt] = 0.f; }
    if (yok) {
#pragma unroll
      for (int Mt = 0; Mt < 2; ++Mt)
#pragma unroll
        for (int r = 0; r < 16; ++r) {
          int m = (r & 3) + 8 * (r >> 2) + 4 * lh;
          int x = x0 + Mt * 32 + m;
          if (x < W) {
#pragma unroll
            for (int nt = 0; nt < NT; ++nt) {
              float v = acc[Mt][nt][r];
              s1[nt] += v;
              s2[nt] += v * v;
            }
          }
        }
    }
#pragma unroll
    for (int nt = 0; nt < NT; ++nt) {
      s1[nt] += __shfl_xor(s1[nt], 32);
      s2[nt] += __shfl_xor(s2[nt], 32);
    }
    __syncthreads();  // all MFMA LDS reads done; reuse s_in as fp32 scratch
    float* red = (float*)s_in;
    if (lh == 0) {
#pragma unroll
      for (int nt = 0; nt < NT; ++nt) {
        red[(wv * NT + nt) * 32 + lc] = s1[nt];
        red[WAVES * NT * 32 + (wv * NT + nt) * 32 + lc] = s2[nt];
      }
    }
    __syncthreads();
    if (wv == 0 && lh == 0) {
#pragma unroll
      for (int nt = 0; nt < NT; ++nt) {
        float a = 0.f, b = 0.f;
#pragma unroll
        for (int w8 = 0; w8 < WAVES; ++w8) {
          a += red[(w8 * NT + nt) * 32 + lc];
          b += red[WAVES * NT * 32 + (w8 * NT + nt) * 32 + lc];
        }
        int ch = (z * NT + nt) * 32 + lc;
        atomicAdd(&statacc[ch], a);
        atomicAdd(&statacc[ch + 256], b);
      }
    }
  }

  if (POOL) {
    const int OWp = W >> 1, OHp = H >> 1;
    float hm[2][NT][8];
#pragma unroll
    for (int Mt = 0; Mt < 2; ++Mt)
#pragma unroll
      for (int nt = 0; nt < NT; ++nt)
#pragma unroll
        for (int i = 0; i < 8; ++i)
          hm[Mt][nt][i] = fmaxf(acc[Mt][nt][2 * i], acc[Mt][nt][2 * i + 1]);
    __syncthreads();
    float* pl = (float*)s_in;
    if (wv & 1) {
#pragma unroll
      for (int Mt = 0; Mt < 2; ++Mt)
#pragma unroll
        for (int nt = 0; nt < NT; ++nt)
#pragma unroll
          for (int i = 0; i < 8; ++i)
            pl[((((wv >> 1) * 2 + Mt) * NT + nt) * 8 + i) * 64 + lane] = hm[Mt][nt][i];
    }
    __syncthreads();
    if (!(wv & 1)) {
      int oy = (y0 + wv) >> 1;
      if (oy < OHp) {
#pragma unroll
        for (int Mt = 0; Mt < 2; ++Mt)
#pragma unroll
          for (int i = 0; i < 8; ++i) {
            int pxl = Mt * 16 + (i >> 1) * 4 + (i & 1) + 2 * lh;
            int ox = (x0 >> 1) + pxl;
            if (ox < OWp) {
#pragma unroll
              for (int nt = 0; nt < NT; ++nt) {
                float v = fmaxf(
                    hm[Mt][nt][i],
                    pl[((((wv >> 1) * 2 + Mt) * NT + nt) * 8 + i) * 64 + lane]);
                int oc = (z * NT + nt) * 32 + lc;
                obf[((size_t)oy * OWp + ox) * Ntot + oc] = f2bf(v);
              }
            }
          }
      }
    }
  }
}

// ------------------------------------------------------------------
// Head reduce: sum nz HWC(x32) fp32 partial slices -> 24 CHW planes.
// ------------------------------------------------------------------

__global__ __launch_bounds__(256) void head_reduce(const float* __restrict__ hp,
                                                   float* __restrict__ out, int HW,
                                                   int nz) {
  __shared__ float t[256 * 33];
  int tid = threadIdx.x;
  int sp0 = blockIdx.x * 256;
  int lim = (HW - sp0) * 32;
#pragma unroll 4
  for (int i = 0; i < 32; ++i) {
    int e = i * 256 + tid;
    float s = 0.f;
    if (e < lim) {
      size_t gidx = (size_t)sp0 * 32 + e;
      for (int z = 0; z < nz; ++z) s += hp[(size_t)z * HW * 32 + gidx];
    }
    t[(e >> 5) * 33 + (e & 31)] = s;
  }
  __syncthreads();
  int sp = sp0 + tid;
  if (sp < HW) {
#pragma unroll
    for (int ch = 0; ch < 24; ++ch)
      out[(size_t)ch * HW + sp] = t[tid * 33 + ch];
  }
}

// ------------------------------------------------------------------

extern "C" void kernel_launch(void* const* d_in, const int* in_sizes, int n_in,
                              void* d_out, int out_size, void* d_ws, size_t ws_size,
                              hipStream_t stream) {
  (void)in_sizes; (void)n_in; (void)out_size; (void)ws_size;
  const float* pillars = (const float*)d_in[0];
  const int* coords = (const int*)d_in[1];
  const float* lin_w = (const float*)d_in[2];
  const float* lin_b = (const float*)d_in[3];
  const float* pfn_g = (const float*)d_in[4];
  const float* pfn_b = (const float*)d_in[5];
  const float* c1_w = (const float*)d_in[6];
  const float* c1_b = (const float*)d_in[7];
  const float* bn1_g = (const float*)d_in[8];
  const float* bn1_b = (const float*)d_in[9];
  const float* c2_w = (const float*)d_in[10];
  const float* c2_b = (const float*)d_in[11];
  const float* bn2_g = (const float*)d_in[12];
  const float* bn2_b = (const float*)d_in[13];
  const float* h1_w = (const float*)d_in[14];
  const float* h1_b = (const float*)d_in[15];
  const float* hbn_g = (const float*)d_in[16];
  const float* hbn_b = (const float*)d_in[17];
  const float* hb_w = (const float*)d_in[18];
  const float* hb_b = (const float*)d_in[19];
  const float* hc_w = (const float*)d_in[20];
  const float* hc_b = (const float*)d_in[21];
  float* out = (float*)d_out;

  // ---- workspace layout (bytes) ----
  char* ws = (char*)d_ws;
  float* pfn_acc = (float*)(ws + 0);         // 512 B
  float* pfn_ss  = (float*)(ws + 512);       // 512 B
  float* bn_acc1 = (float*)(ws + 1024);      // 2048 B
  float* bn_acc2 = (float*)(ws + 3072);      // 2048 B
  float* bn_acc3 = (float*)(ws + 5120);      // 2048 B
  float* coef1   = (float*)(ws + 7168);      // 512 B
  float* coef2   = (float*)(ws + 7680);      // 1024 B
  float* coef3   = (float*)(ws + 8704);      // 2048 B
  int* winner    = (int*)(ws + 10752);       // 1774224 B
  ushort_t* feats  = (ushort_t*)(ws + 1785088);    // 20000x64 bf16 = 2560000 B
  ushort_t* c1p    = (ushort_t*)(ws + 4345088);    // 333x333x64  = 14193792 B (pooled raw)
  ushort_t* c2p    = (ushort_t*)(ws + 18538880);   // 166x166x128 = 7054336 B (pooled raw)
  ushort_t* h1out  = (ushort_t*)(ws + 25593216);   // 166x166x256 = 14108672 B (raw)
  ushort_t* w2c1   = (ushort_t*)(ws + 39701888);   // 73728 B
  ushort_t* w2c2   = (ushort_t*)(ws + 39775616);   // 147456 B
  ushort_t* w2h1   = (ushort_t*)(ws + 39923072);   // 589824 B
  ushort_t* w2hd   = (ushort_t*)(ws + 40512896);   // 147456 B
  float* hpart     = (float*)(ws + 40660352);      // 4x27556x32x4 = 14108672 B

  const int HW3 = 166 * 166;

  // ---- upfront zero-init ----
  hipMemsetAsync(ws, 0, 10752, stream);
  hipMemsetAsync(winner, 0xFF, 1774224, stream);

  // ---- weight prep (merged) ----
  prep_all<<<234, 256, 0, stream>>>(c1_w, c2_w, h1_w, hb_w, hc_w, w2c1, w2c2, w2h1,
                                    w2hd);

  // ---- PFN ----
  pfn_stats<<<625, 256, 0, stream>>>(pillars, lin_w, lin_b, pfn_acc);
  pfn_finalize<<<1, 64, 0, stream>>>(pfn_acc, pfn_g, pfn_b, pfn_ss);
  pfn_feats<<<5000, 256, 0, stream>>>(pillars, lin_w, lin_b, pfn_ss, feats);

  // ---- scatter winner map ----
  scatter_winner<<<(20000 + 255) / 256, 256, 0, stream>>>(coords, winner, 20000);

  // ---- conv1: gather-staged from winner/feats(bf16), stats + pool -> c1p ----
  conv_mfma<2, 8, 2, false, true, true><<<dim3(11, 84, 1), 512, 0, stream>>>(
      nullptr, winner, feats, w2c1, c1_b, nullptr, nullptr, c1p, nullptr, bn_acc1, 666,
      666, 64, 2, 2);
  bn_make_coefs<<<1, 64, 0, stream>>>(bn_acc1, bn1_g, bn1_b, 1.f / 443556.f, coef1, 64);

  // ---- conv2: BN-staged from c1p raw, stats + pool -> c2p ----
  conv_mfma<2, 8, 1, false, true, true><<<dim3(6, 42, 2), 512, 0, stream>>>(
      c1p, nullptr, nullptr, w2c2, c2_b, nullptr, coef1, c2p, nullptr, bn_acc2, 333, 333,
      64, 2, 4);
  bn_make_coefs<<<1, 128, 0, stream>>>(bn_acc2, bn2_g, bn2_b, 1.f / 110889.f, coef2, 128);

  // ---- h1: BN-staged from c2p raw, NT=2 WAVES=4 oc-split z=4 (stats) ----
  conv_mfma<2, 4, 1, false, true, false><<<dim3(3, 42, 4), 256, 0, stream>>>(
      c2p, nullptr, nullptr, w2h1, h1_b, nullptr, coef2, h1out, nullptr, bn_acc3, 166,
      166, 128, 4, 8);
  bn_make_coefs<<<1, 256, 0, stream>>>(bn_acc3, hbn_g, hbn_b, 1.f / 27556.f, coef3, 256);

  // ---- heads: BN-staged from h1out raw, K-split z=4, coalesced partials ----
  conv_mfma<1, 4, 1, true, false, false><<<dim3(3, 42, 4), 256, 0, stream>>>(
      h1out, nullptr, nullptr, w2hd, hb_b, hc_b, coef3, nullptr, hpart, nullptr, 166,
      166, 256, 2, 1);
  head_reduce<<<(HW3 + 255) / 256, 256, 0, stream>>>(hpart, out, HW3, 4);
}

// Round 14
// 323.888 us; speedup vs baseline: 1.4469x; 1.0956x over previous
//
#include <hip/hip_runtime.h>
#include <hip/hip_bf16.h>
#include <cstdint>
#include <cstddef>

#define BN_EPS 1e-5f

typedef short short8 __attribute__((ext_vector_type(8)));
typedef float float16 __attribute__((ext_vector_type(16)));
typedef unsigned short ushort_t;

__device__ __forceinline__ float bf2f(ushort_t u) {
  return __uint_as_float(((unsigned int)u) << 16);
}
__device__ __forceinline__ ushort_t f2bf(float f) {
  unsigned int u = __float_as_uint(f);
  u += 0x7FFFu + ((u >> 16) & 1u);
  return (ushort_t)(u >> 16);
}

// ------------------------------------------------------------------
// PFN stats via moments: S = sum x (9), M = sum x x^T (45 upper-tri).
// y = xW^T+b is affine in x, so per-channel mean/var derive from S,M.
// ------------------------------------------------------------------

__global__ __launch_bounds__(512) void pillar_moments(
    const float* __restrict__ pillars, float* __restrict__ mom) {
  float S[9], M[45];
#pragma unroll
  for (int i = 0; i < 9; ++i) S[i] = 0.f;
#pragma unroll
  for (int i = 0; i < 45; ++i) M[i] = 0.f;
  const int t = blockIdx.x * 512 + threadIdx.x;
  const int NTH = 128 * 512;
  for (long r = t; r < 640000; r += NTH) {
    float x[9];
    const float* rp = pillars + r * 9;
#pragma unroll
    for (int d = 0; d < 9; ++d) x[d] = rp[d];
    int k = 0;
#pragma unroll
    for (int i = 0; i < 9; ++i) {
      S[i] += x[i];
#pragma unroll
      for (int j = i; j < 9; ++j) { M[k] += x[i] * x[j]; ++k; }
    }
  }
  // wave reduction
#pragma unroll
  for (int i = 0; i < 9; ++i)
#pragma unroll
    for (int o = 32; o > 0; o >>= 1) S[i] += __shfl_xor(S[i], o);
#pragma unroll
  for (int i = 0; i < 45; ++i)
#pragma unroll
    for (int o = 32; o > 0; o >>= 1) M[i] += __shfl_xor(M[i], o);
  __shared__ float red[8 * 54];
  int lane = threadIdx.x & 63, wv = threadIdx.x >> 6;
  if (lane == 0) {
#pragma unroll
    for (int i = 0; i < 9; ++i) red[wv * 54 + i] = S[i];
#pragma unroll
    for (int i = 0; i < 45; ++i) red[wv * 54 + 9 + i] = M[i];
  }
  __syncthreads();
  if (threadIdx.x < 54) {
    float s = 0.f;
#pragma unroll
    for (int w8 = 0; w8 < 8; ++w8) s += red[w8 * 54 + threadIdx.x];
    atomicAdd(&mom[threadIdx.x], s);
  }
}

// 64 threads; double-precision algebra from moments -> scale/shift
__global__ void pfn_finalize(const float* __restrict__ mom,
                             const float* __restrict__ lin_w,
                             const float* __restrict__ lin_b,
                             const float* __restrict__ g, const float* __restrict__ b,
                             float* __restrict__ ss) {
  int c = threadIdx.x;
  double w[9], S[9];
#pragma unroll
  for (int d = 0; d < 9; ++d) {
    w[d] = (double)lin_w[c * 9 + d];
    S[d] = (double)mom[d];
  }
  double wS = 0.0;
#pragma unroll
  for (int d = 0; d < 9; ++d) wS += w[d] * S[d];
  double wMw = 0.0;
  int k = 0;
#pragma unroll
  for (int i = 0; i < 9; ++i)
#pragma unroll
    for (int j = i; j < 9; ++j) {
      double m = (double)mom[9 + k];
      wMw += (i == j ? 1.0 : 2.0) * w[i] * w[j] * m;
      ++k;
    }
  const double N = 640000.0;
  double bc = (double)lin_b[c];
  double mean = (wS + N * bc) / N;
  double ey2 = (wMw + 2.0 * bc * wS + N * bc * bc) / N;
  double var = ey2 - mean * mean;
  if (var < 0.0) var = 0.0;
  double inv = 1.0 / sqrt(var + (double)BN_EPS);
  double sc = (double)g[c] * inv;
  ss[c] = (float)sc;
  ss[c + 64] = (float)((double)b[c] - mean * sc);
}

__global__ __launch_bounds__(256) void pfn_feats(
    const float* __restrict__ pillars, const float* __restrict__ lin_w,
    const float* __restrict__ lin_b, const float* __restrict__ ss,
    ushort_t* __restrict__ feats) {
  __shared__ float s_p[1152];
  int tid = threadIdx.x;
  int c = tid & 63, pe = tid >> 6;
  long pb = (long)blockIdx.x * 4;
  for (int i = tid; i < 1152; i += 256) s_p[i] = pillars[pb * 288 + i];
  float w[9];
#pragma unroll
  for (int d = 0; d < 9; ++d) w[d] = lin_w[c * 9 + d];
  float bl = lin_b[c];
  float sc = ss[c], sh = ss[c + 64];
  __syncthreads();
  const float* pp = &s_p[pe * 288];
  float m = -1e30f;
#pragma unroll 4
  for (int n = 0; n < 32; ++n) {
    float y = bl;
#pragma unroll
    for (int d = 0; d < 9; ++d) y += pp[n * 9 + d] * w[d];
    float v = fmaxf(y * sc + sh, 0.f);
    m = fmaxf(m, v);
  }
  feats[(pb + pe) * 64 + c] = f2bf(m);
}

// ------------------------------------------------------------------
// Scatter winner map (numpy last-write-wins)
// ------------------------------------------------------------------

__global__ void scatter_winner(const int* __restrict__ coords, int* __restrict__ winner,
                               int P) {
  int p = blockIdx.x * 256 + threadIdx.x;
  if (p >= P) return;
  int y = coords[p * 3 + 1], x = coords[p * 3 + 2];
  if (y >= 0 && y < 666 && x >= 0 && x < 666) atomicMax(&winner[y * 666 + x], p);
}

// ------------------------------------------------------------------
// Weight prep (merged): OIHW fp32 -> fragment-ordered bf16 (Kc=32 layout)
// ------------------------------------------------------------------

__device__ __forceinline__ void prep_one(const float* __restrict__ w,
                                         ushort_t* __restrict__ w2, int C, int N,
                                         int Ntg, int chunks, int u) {
  int total = chunks * 9 * 2 * Ntg * 64;
  if (u >= total) return;
  int l = u & 63;
  int g = u >> 6;
  int ntg = g % Ntg;
  int g2 = g / Ntg;
  int s = g2 & 1;
  int g3 = g2 >> 1;
  int pos = g3 % 9;
  int cc = g3 / 9;
  int n = ntg * 32 + (l & 31);
  int c0 = cc * 32 + s * 16 + (l >> 5) * 8;
  ushort_t o8[8];
#pragma unroll
  for (int j = 0; j < 8; ++j) {
    int c = c0 + j;
    float v = (n < N && c < C) ? w[((size_t)n * C + c) * 9 + pos] : 0.f;
    o8[j] = f2bf(v);
  }
  *(uint4*)&w2[(size_t)u * 8] = *(const uint4*)o8;
}

__device__ __forceinline__ void prep_head_one(const float* __restrict__ hb,
                                              const float* __restrict__ hc,
                                              ushort_t* __restrict__ w2, int u) {
  int total = 8 * 9 * 2 * 64;
  if (u >= total) return;
  int l = u & 63;
  int g = u >> 6;
  int s = g & 1;
  int g3 = g >> 1;
  int pos = g3 % 9;
  int cc = g3 / 9;
  int n = l & 31;
  int c0 = cc * 32 + s * 16 + (l >> 5) * 8;
  ushort_t o8[8];
#pragma unroll
  for (int j = 0; j < 8; ++j) {
    int c = c0 + j;
    float v = 0.f;
    if (n < 21) v = hb[((size_t)n * 256 + c) * 9 + pos];
    else if (n < 24) v = hc[((size_t)(n - 21) * 256 + c) * 9 + pos];
    o8[j] = f2bf(v);
  }
  *(uint4*)&w2[(size_t)u * 8] = *(const uint4*)o8;
}

// grid 234 x 256
__global__ void prep_all(const float* __restrict__ c1_w, const float* __restrict__ c2_w,
                         const float* __restrict__ h1_w, const float* __restrict__ hb_w,
                         const float* __restrict__ hc_w, ushort_t* __restrict__ w2c1,
                         ushort_t* __restrict__ w2c2, ushort_t* __restrict__ w2h1,
                         ushort_t* __restrict__ w2hd) {
  int b = blockIdx.x;
  int t = threadIdx.x;
  if (b < 18) prep_one(c1_w, w2c1, 64, 64, 2, 2, b * 256 + t);
  else if (b < 54) prep_one(c2_w, w2c2, 64, 128, 4, 2, (b - 18) * 256 + t);
  else if (b < 198) prep_one(h1_w, w2h1, 128, 256, 8, 4, (b - 54) * 256 + t);
  else prep_head_one(hb_w, hc_w, w2hd, (b - 198) * 256 + t);
}

// ------------------------------------------------------------------
// BN coef publish
// ------------------------------------------------------------------

__global__ void bn_make_coefs(const float* __restrict__ acc, const float* __restrict__ g,
                              const float* __restrict__ b, float invN,
                              float* __restrict__ coef, int C) {
  int c = threadIdx.x;
  if (c >= C) return;
  float m = acc[c] * invN;
  float v = fmaxf(acc[c + 256] * invN - m * m, 0.f);
  float sc = g[c] * rsqrtf(v + BN_EPS);
  coef[c] = sc;
  coef[C + c] = b[c] - m * sc;
}

// ------------------------------------------------------------------
// Implicit-GEMM 3x3 conv via v_mfma_f32_32x32x16_bf16.
// MODE 1: BN-stage from raw unpadded HWC: relu(x*sc+sh), bounds->0.
// MODE 2: gather-stage (conv1): winner[cell] -> bf16 feats row, miss->0.
// Per-position addressing/bounds/winner hoisted OUT of the K-chunk loop.
// HEAD: z = K-split; coalesced fp32 partials. STATS: fused BN stats.
// POOL: fused raw 2x2 max-pool (BN scale > 0 -> monotone).
// ------------------------------------------------------------------

template <int NT, int WAVES, int MODE, bool HEAD, bool STATS, bool POOL>
__global__ __launch_bounds__(WAVES * 64, WAVES == 8 ? 4 : 3) void conv_mfma(
    const ushort_t* __restrict__ in, const int* __restrict__ winner,
    const ushort_t* __restrict__ feats, const ushort_t* __restrict__ w2,
    const float* __restrict__ bias, const float* __restrict__ bias2,
    const float* __restrict__ coef_in, ushort_t* __restrict__ obf,
    float* __restrict__ hpart, float* __restrict__ statacc, int W, int H, int C,
    int nchunks, int Ntg) {
  constexpr int NTHREADS = WAVES * 64;
  __shared__ ushort_t s_in[(WAVES + 2) * 66 * 32];
  __shared__ ushort_t s_w[9 * 2 * NT * 512];
  const int tid = threadIdx.x;
  const int lane = tid & 63, wv = tid >> 6;
  const int lc = lane & 31, lh = lane >> 5;
  const int x0 = blockIdx.x * 64, y0 = blockIdx.y * WAVES;
  const int z = blockIdx.z;
  const int cc0 = HEAD ? z * nchunks : 0;
  const int z_oc = HEAD ? 0 : z;

  // per-lane A-address precompute
  int pc[2][2][3];
#pragma unroll
  for (int s = 0; s < 2; ++s)
#pragma unroll
    for (int Mt = 0; Mt < 2; ++Mt)
#pragma unroll
      for (int kx = 0; kx < 3; ++kx) {
        int col = Mt * 32 + kx + lc;
        int q = (2 * s + lh) ^ ((col >> 1) & 3);
        pc[s][Mt][kx] = col * 32 + q * 8;
      }

  // ---- hoisted staging descriptors ----
  const int sg = tid & 3;
  const int tpos = tid >> 2;
  constexpr int TPOS = NTHREADS / 4;
  constexpr int NPOS = (WAVES + 2) * 66;
  constexpr int NIT = (NPOS + TPOS - 1) / TPOS;
  int ldst[NIT], gsrc[NIT];
#pragma unroll
  for (int it = 0; it < NIT; ++it) {
    ldst[it] = -1;
    gsrc[it] = -1;
    int p = tpos + it * TPOS;
    if (p < NPOS) {
      int r = p / 66, col = p - r * 66;
      int f = sg ^ ((col >> 1) & 3);
      ldst[it] = (r * 66 + col) * 32 + f * 8;
      int gy = y0 - 1 + r, gx = x0 - 1 + col;
      if (gy >= 0 && gy < H && gx >= 0 && gx < W) {
        if (MODE == 2) {
          int pw = winner[gy * 666 + gx];
          if (pw >= 0) gsrc[it] = pw * 64 + sg * 8;
        } else {
          gsrc[it] = (gy * W + gx) * C + sg * 8;
        }
      }
    }
  }

  float bv[NT];
#pragma unroll
  for (int nt = 0; nt < NT; ++nt) {
    if (HEAD) {
      bv[nt] = (z == 0) ? (lc < 21 ? bias[lc] : (lc < 24 ? bias2[lc - 21] : 0.f)) : 0.f;
    } else {
      bv[nt] = bias[(z * NT + nt) * 32 + lc];
    }
  }
  float16 acc[2][NT];
#pragma unroll
  for (int Mt = 0; Mt < 2; ++Mt)
#pragma unroll
    for (int nt = 0; nt < NT; ++nt)
#pragma unroll
      for (int r = 0; r < 16; ++r) acc[Mt][nt][r] = bv[nt];

  for (int cc = 0; cc < nchunks; ++cc) {
    const int ccg = cc0 + cc;
    __syncthreads();
    if (MODE == 2) {
#pragma unroll
      for (int it = 0; it < NIT; ++it) {
        if (ldst[it] < 0) continue;
        uint4 v = make_uint4(0, 0, 0, 0);
        if (gsrc[it] >= 0) v = *(const uint4*)&feats[gsrc[it] + ccg * 32];
        *(uint4*)&s_in[ldst[it]] = v;
      }
    } else {  // MODE 1
      float sc8[8], sh8[8];
      {
        int ch = ccg * 32 + sg * 8;
        float4 a0 = *(const float4*)&coef_in[ch];
        float4 a1 = *(const float4*)&coef_in[ch + 4];
        float4 b0 = *(const float4*)&coef_in[C + ch];
        float4 b1 = *(const float4*)&coef_in[C + ch + 4];
        sc8[0] = a0.x; sc8[1] = a0.y; sc8[2] = a0.z; sc8[3] = a0.w;
        sc8[4] = a1.x; sc8[5] = a1.y; sc8[6] = a1.z; sc8[7] = a1.w;
        sh8[0] = b0.x; sh8[1] = b0.y; sh8[2] = b0.z; sh8[3] = b0.w;
        sh8[4] = b1.x; sh8[5] = b1.y; sh8[6] = b1.z; sh8[7] = b1.w;
      }
#pragma unroll
      for (int it = 0; it < NIT; ++it) {
        if (ldst[it] < 0) continue;
        ushort_t v8[8] = {0, 0, 0, 0, 0, 0, 0, 0};
        if (gsrc[it] >= 0) {
          uint4 raw = *(const uint4*)&in[gsrc[it] + ccg * 32];
          const ushort_t* rp = (const ushort_t*)&raw;
#pragma unroll
          for (int j = 0; j < 8; ++j)
            v8[j] = f2bf(fmaxf(bf2f(rp[j]) * sc8[j] + sh8[j], 0.f));
        }
        *(uint4*)&s_in[ldst[it]] = *(const uint4*)v8;
      }
    }
    // stage weight slice
    const int NW = NT * 1152;
    for (int u = tid; u < NW; u += NTHREADS) {
      int l16 = u & 63, grp = u >> 6;
      int nt = grp % NT, ps = grp / NT;
      const ushort_t* src =
          w2 + ((size_t)((ccg * 18 + ps) * Ntg + z_oc * NT + nt) * 64 + l16) * 8;
      *(uint4*)&s_w[(size_t)u * 8] = *(const uint4*)src;
    }
    __syncthreads();
#pragma unroll
    for (int ky = 0; ky < 3; ++ky) {
      int rowoff = (wv + ky) * (66 * 32);
#pragma unroll
      for (int kx = 0; kx < 3; ++kx) {
        const int pos = ky * 3 + kx;
#pragma unroll
        for (int s = 0; s < 2; ++s) {
          short8 Bf[NT];
#pragma unroll
          for (int nt = 0; nt < NT; ++nt)
            Bf[nt] = *(const short8*)&s_w[((pos * 2 + s) * NT + nt) * 512 + lane * 8];
#pragma unroll
          for (int Mt = 0; Mt < 2; ++Mt) {
            short8 Af = *(const short8*)&s_in[rowoff + pc[s][Mt][kx]];
#pragma unroll
            for (int nt = 0; nt < NT; ++nt)
              acc[Mt][nt] =
                  __builtin_amdgcn_mfma_f32_32x32x16_bf16(Af, Bf[nt], acc[Mt][nt], 0, 0, 0);
          }
        }
      }
    }
  }

  // ---- epilogue ----
  const int y = y0 + wv;
  const bool yok = (y < H);
  const int Ntot = Ntg * 32;

  if (HEAD) {
    if (yok) {
      float* hp = hpart + (size_t)z * (size_t)(H * W) * 32;
#pragma unroll
      for (int Mt = 0; Mt < 2; ++Mt)
#pragma unroll
        for (int r = 0; r < 16; ++r) {
          int m = (r & 3) + 8 * (r >> 2) + 4 * lh;
          int x = x0 + Mt * 32 + m;
          if (x < W) {
            size_t sp = (size_t)y * W + x;
            hp[sp * 32 + lc] = acc[Mt][0][r];  // coalesced
          }
        }
    }
    return;
  }

  if (!POOL) {
    if (yok) {
#pragma unroll
      for (int Mt = 0; Mt < 2; ++Mt)
#pragma unroll
        for (int r = 0; r < 16; ++r) {
          int m = (r & 3) + 8 * (r >> 2) + 4 * lh;
          int x = x0 + Mt * 32 + m;
          if (x < W) {
            size_t sp = (size_t)y * W + x;
#pragma unroll
            for (int nt = 0; nt < NT; ++nt) {
              int oc = (z * NT + nt) * 32 + lc;
              obf[sp * Ntot + oc] = f2bf(acc[Mt][nt][r]);
            }
          }
        }
    }
  }

  if (STATS) {
    float s1[NT], s2[NT];
#pragma unroll
    for (int nt = 0; nt < NT; ++nt) { s1[nt] = 0.f; s2[nt] = 0.f; }
    if (yok) {
#pragma unroll
      for (int Mt = 0; Mt < 2; ++Mt)
#pragma unroll
        for (int r = 0; r < 16; ++r) {
          int m = (r & 3) + 8 * (r >> 2) + 4 * lh;
          int x = x0 + Mt * 32 + m;
          if (x < W) {
#pragma unroll
            for (int nt = 0; nt < NT; ++nt) {
              float v = acc[Mt][nt][r];
              s1[nt] += v;
              s2[nt] += v * v;
            }
          }
        }
    }
#pragma unroll
    for (int nt = 0; nt < NT; ++nt) {
      s1[nt] += __shfl_xor(s1[nt], 32);
      s2[nt] += __shfl_xor(s2[nt], 32);
    }
    __syncthreads();  // all MFMA LDS reads done; reuse s_in as fp32 scratch
    float* red = (float*)s_in;
    if (lh == 0) {
#pragma unroll
      for (int nt = 0; nt < NT; ++nt) {
        red[(wv * NT + nt) * 32 + lc] = s1[nt];
        red[WAVES * NT * 32 + (wv * NT + nt) * 32 + lc] = s2[nt];
      }
    }
    __syncthreads();
    if (wv == 0 && lh == 0) {
#pragma unroll
      for (int nt = 0; nt < NT; ++nt) {
        float a = 0.f, b = 0.f;
#pragma unroll
        for (int w8 = 0; w8 < WAVES; ++w8) {
          a += red[(w8 * NT + nt) * 32 + lc];
          b += red[WAVES * NT * 32 + (w8 * NT + nt) * 32 + lc];
        }
        int ch = (z * NT + nt) * 32 + lc;
        atomicAdd(&statacc[ch], a);
        atomicAdd(&statacc[ch + 256], b);
      }
    }
  }

  if (POOL) {
    const int OWp = W >> 1, OHp = H >> 1;
    float hm[2][NT][8];
#pragma unroll
    for (int Mt = 0; Mt < 2; ++Mt)
#pragma unroll
      for (int nt = 0; nt < NT; ++nt)
#pragma unroll
        for (int i = 0; i < 8; ++i)
          hm[Mt][nt][i] = fmaxf(acc[Mt][nt][2 * i], acc[Mt][nt][2 * i + 1]);
    __syncthreads();
    float* pl = (float*)s_in;
    if (wv & 1) {
#pragma unroll
      for (int Mt = 0; Mt < 2; ++Mt)
#pragma unroll
        for (int nt = 0; nt < NT; ++nt)
#pragma unroll
          for (int i = 0; i < 8; ++i)
            pl[((((wv >> 1) * 2 + Mt) * NT + nt) * 8 + i) * 64 + lane] = hm[Mt][nt][i];
    }
    __syncthreads();
    if (!(wv & 1)) {
      int oy = (y0 + wv) >> 1;
      if (oy < OHp) {
#pragma unroll
        for (int Mt = 0; Mt < 2; ++Mt)
#pragma unroll
          for (int i = 0; i < 8; ++i) {
            int pxl = Mt * 16 + (i >> 1) * 4 + (i & 1) + 2 * lh;
            int ox = (x0 >> 1) + pxl;
            if (ox < OWp) {
#pragma unroll
              for (int nt = 0; nt < NT; ++nt) {
                float v = fmaxf(
                    hm[Mt][nt][i],
                    pl[((((wv >> 1) * 2 + Mt) * NT + nt) * 8 + i) * 64 + lane]);
                int oc = (z * NT + nt) * 32 + lc;
                obf[((size_t)oy * OWp + ox) * Ntot + oc] = f2bf(v);
              }
            }
          }
      }
    }
  }
}

// ------------------------------------------------------------------
// Head reduce: sum nz HWC(x32) fp32 partial slices -> 24 CHW planes.
// ------------------------------------------------------------------

__global__ __launch_bounds__(256) void head_reduce(const float* __restrict__ hp,
                                                   float* __restrict__ out, int HW,
                                                   int nz) {
  __shared__ float t[256 * 33];
  int tid = threadIdx.x;
  int sp0 = blockIdx.x * 256;
  int lim = (HW - sp0) * 32;
#pragma unroll 4
  for (int i = 0; i < 32; ++i) {
    int e = i * 256 + tid;
    float s = 0.f;
    if (e < lim) {
      size_t gidx = (size_t)sp0 * 32 + e;
      for (int z = 0; z < nz; ++z) s += hp[(size_t)z * HW * 32 + gidx];
    }
    t[(e >> 5) * 33 + (e & 31)] = s;
  }
  __syncthreads();
  int sp = sp0 + tid;
  if (sp < HW) {
#pragma unroll
    for (int ch = 0; ch < 24; ++ch)
      out[(size_t)ch * HW + sp] = t[tid * 33 + ch];
  }
}

// ------------------------------------------------------------------

extern "C" void kernel_launch(void* const* d_in, const int* in_sizes, int n_in,
                              void* d_out, int out_size, void* d_ws, size_t ws_size,
                              hipStream_t stream) {
  (void)in_sizes; (void)n_in; (void)out_size; (void)ws_size;
  const float* pillars = (const float*)d_in[0];
  const int* coords = (const int*)d_in[1];
  const float* lin_w = (const float*)d_in[2];
  const float* lin_b = (const float*)d_in[3];
  const float* pfn_g = (const float*)d_in[4];
  const float* pfn_b = (const float*)d_in[5];
  const float* c1_w = (const float*)d_in[6];
  const float* c1_b = (const float*)d_in[7];
  const float* bn1_g = (const float*)d_in[8];
  const float* bn1_b = (const float*)d_in[9];
  const float* c2_w = (const float*)d_in[10];
  const float* c2_b = (const float*)d_in[11];
  const float* bn2_g = (const float*)d_in[12];
  const float* bn2_b = (const float*)d_in[13];
  const float* h1_w = (const float*)d_in[14];
  const float* h1_b = (const float*)d_in[15];
  const float* hbn_g = (const float*)d_in[16];
  const float* hbn_b = (const float*)d_in[17];
  const float* hb_w = (const float*)d_in[18];
  const float* hb_b = (const float*)d_in[19];
  const float* hc_w = (const float*)d_in[20];
  const float* hc_b = (const float*)d_in[21];
  float* out = (float*)d_out;

  // ---- workspace layout (bytes) ----
  char* ws = (char*)d_ws;
  float* mom     = (float*)(ws + 0);         // 54 floats (S[9], M[45])
  float* pfn_ss  = (float*)(ws + 512);       // 512 B
  float* bn_acc1 = (float*)(ws + 1024);      // 2048 B
  float* bn_acc2 = (float*)(ws + 3072);      // 2048 B
  float* bn_acc3 = (float*)(ws + 5120);      // 2048 B
  float* coef1   = (float*)(ws + 7168);      // 512 B
  float* coef2   = (float*)(ws + 7680);      // 1024 B
  float* coef3   = (float*)(ws + 8704);      // 2048 B
  int* winner    = (int*)(ws + 10752);       // 1774224 B
  ushort_t* feats  = (ushort_t*)(ws + 1785088);    // 20000x64 bf16 = 2560000 B
  ushort_t* c1p    = (ushort_t*)(ws + 4345088);    // 333x333x64  = 14193792 B (pooled raw)
  ushort_t* c2p    = (ushort_t*)(ws + 18538880);   // 166x166x128 = 7054336 B (pooled raw)
  ushort_t* h1out  = (ushort_t*)(ws + 25593216);   // 166x166x256 = 14108672 B (raw)
  ushort_t* w2c1   = (ushort_t*)(ws + 39701888);   // 73728 B
  ushort_t* w2c2   = (ushort_t*)(ws + 39775616);   // 147456 B
  ushort_t* w2h1   = (ushort_t*)(ws + 39923072);   // 589824 B
  ushort_t* w2hd   = (ushort_t*)(ws + 40512896);   // 147456 B
  float* hpart     = (float*)(ws + 40660352);      // 4x27556x32x4 = 14108672 B

  const int HW3 = 166 * 166;

  // ---- upfront zero-init ----
  hipMemsetAsync(ws, 0, 10752, stream);
  hipMemsetAsync(winner, 0xFF, 1774224, stream);

  // ---- weight prep (merged) ----
  prep_all<<<234, 256, 0, stream>>>(c1_w, c2_w, h1_w, hb_w, hc_w, w2c1, w2c2, w2h1,
                                    w2hd);

  // ---- PFN: moments-based stats, then feats ----
  pillar_moments<<<128, 512, 0, stream>>>(pillars, mom);
  pfn_finalize<<<1, 64, 0, stream>>>(mom, lin_w, lin_b, pfn_g, pfn_b, pfn_ss);
  pfn_feats<<<5000, 256, 0, stream>>>(pillars, lin_w, lin_b, pfn_ss, feats);

  // ---- scatter winner map ----
  scatter_winner<<<(20000 + 255) / 256, 256, 0, stream>>>(coords, winner, 20000);

  // ---- conv1: gather-staged from winner/feats(bf16), stats + pool -> c1p ----
  conv_mfma<2, 8, 2, false, true, true><<<dim3(11, 84, 1), 512, 0, stream>>>(
      nullptr, winner, feats, w2c1, c1_b, nullptr, nullptr, c1p, nullptr, bn_acc1, 666,
      666, 64, 2, 2);
  bn_make_coefs<<<1, 64, 0, stream>>>(bn_acc1, bn1_g, bn1_b, 1.f / 443556.f, coef1, 64);

  // ---- conv2: BN-staged from c1p raw, stats + pool -> c2p ----
  conv_mfma<2, 8, 1, false, true, true><<<dim3(6, 42, 2), 512, 0, stream>>>(
      c1p, nullptr, nullptr, w2c2, c2_b, nullptr, coef1, c2p, nullptr, bn_acc2, 333, 333,
      64, 2, 4);
  bn_make_coefs<<<1, 128, 0, stream>>>(bn_acc2, bn2_g, bn2_b, 1.f / 110889.f, coef2, 128);

  // ---- h1: BN-staged from c2p raw, NT=2 WAVES=4 oc-split z=4 (stats) ----
  conv_mfma<2, 4, 1, false, true, false><<<dim3(3, 42, 4), 256, 0, stream>>>(
      c2p, nullptr, nullptr, w2h1, h1_b, nullptr, coef2, h1out, nullptr, bn_acc3, 166,
      166, 128, 4, 8);
  bn_make_coefs<<<1, 256, 0, stream>>>(bn_acc3, hbn_g, hbn_b, 1.f / 27556.f, coef3, 256);

  // ---- heads: BN-staged from h1out raw, K-split z=4, coalesced partials ----
  conv_mfma<1, 4, 1, true, false, false><<<dim3(3, 42, 4), 256, 0, stream>>>(
      h1out, nullptr, nullptr, w2hd, hb_b, hc_b, coef3, nullptr, hpart, nullptr, 166,
      166, 256, 2, 1);
  head_reduce<<<(HW3 + 255) / 256, 256, 0, stream>>>(hpart, out, HW3, 4);
}